// Round 1
// baseline (1378.042 us; speedup 1.0000x reference)
//
#include <hip/hip_runtime.h>
#include <math.h>

#define S_LEN  1024
#define DMODEL 1024
#define DH     64

// ---------------------------------------------------------------------------
// Complex GEMM: C[M,N] = A[M,K] * B[N,K]^T  (both row-major, K contiguous)
// M = 2048, N = K = 1024. Tile 64x64, 256 threads, 4x4 complex per thread.
// EPI: 0 = store Cre/Cim arrays
//      1 = apply RoPE rotor (s = row % S_LEN, k = col & 63) then store arrays
//      2 = store interleaved (re,im) pairs into Cre (the final output)
// ---------------------------------------------------------------------------
template<int EPI>
__global__ __launch_bounds__(256)
void cgemm_nt(const float* __restrict__ Are, const float* __restrict__ Aim,
              const float* __restrict__ Bre, const float* __restrict__ Bim,
              float* __restrict__ Cre, float* __restrict__ Cim)
{
    __shared__ float At_re[16][64], At_im[16][64];
    __shared__ float Bt_re[16][64], Bt_im[16][64];

    const int tid = threadIdx.x;
    const int tx  = tid & 15;       // col group: 4 cols
    const int ty  = tid >> 4;       // row group: 4 rows
    const int m0  = blockIdx.x * 64;
    const int n0  = blockIdx.y * 64;

    const int lm = tid >> 2;          // staging row 0..63
    const int lk = (tid & 3) << 2;    // staging k offset 0,4,8,12

    float cre[4][4] = {{0.f}}, cim[4][4] = {{0.f}};

    const size_t aBase = (size_t)(m0 + lm) * DMODEL + lk;
    const size_t bBase = (size_t)(n0 + lm) * DMODEL + lk;

    for (int k0 = 0; k0 < DMODEL; k0 += 16) {
        __syncthreads();
        float4 a_r = *(const float4*)(Are + aBase + k0);
        float4 a_i = *(const float4*)(Aim + aBase + k0);
        float4 b_r = *(const float4*)(Bre + bBase + k0);
        float4 b_i = *(const float4*)(Bim + bBase + k0);
        At_re[lk+0][lm]=a_r.x; At_re[lk+1][lm]=a_r.y; At_re[lk+2][lm]=a_r.z; At_re[lk+3][lm]=a_r.w;
        At_im[lk+0][lm]=a_i.x; At_im[lk+1][lm]=a_i.y; At_im[lk+2][lm]=a_i.z; At_im[lk+3][lm]=a_i.w;
        Bt_re[lk+0][lm]=b_r.x; Bt_re[lk+1][lm]=b_r.y; Bt_re[lk+2][lm]=b_r.z; Bt_re[lk+3][lm]=b_r.w;
        Bt_im[lk+0][lm]=b_i.x; Bt_im[lk+1][lm]=b_i.y; Bt_im[lk+2][lm]=b_i.z; Bt_im[lk+3][lm]=b_i.w;
        __syncthreads();

        #pragma unroll
        for (int k = 0; k < 16; ++k) {
            float4 q4r = *(const float4*)&At_re[k][ty<<2];
            float4 q4i = *(const float4*)&At_im[k][ty<<2];
            float4 w4r = *(const float4*)&Bt_re[k][tx<<2];
            float4 w4i = *(const float4*)&Bt_im[k][tx<<2];
            const float ar[4]={q4r.x,q4r.y,q4r.z,q4r.w};
            const float ai[4]={q4i.x,q4i.y,q4i.z,q4i.w};
            const float br[4]={w4r.x,w4r.y,w4r.z,w4r.w};
            const float bi[4]={w4i.x,w4i.y,w4i.z,w4i.w};
            #pragma unroll
            for (int i = 0; i < 4; ++i)
                #pragma unroll
                for (int j = 0; j < 4; ++j) {
                    // (ar + i*ai) * (br + i*bi)   (no conjugate)
                    cre[i][j] = fmaf(ar[i], br[j], fmaf(-ai[i], bi[j], cre[i][j]));
                    cim[i][j] = fmaf(ar[i], bi[j], fmaf( ai[i], br[j], cim[i][j]));
                }
        }
    }

    const int gm = m0 + (ty << 2);
    const int gn = n0 + (tx << 2);

    if (EPI == 1) {
        // RoPE rotor: angle = (row % S) * 10000^(-(col&63)/64)
        float invf[4];
        #pragma unroll
        for (int j = 0; j < 4; ++j)
            invf[j] = powf(10000.f, -(float)((gn + j) & 63) * (1.f / 64.f));
        #pragma unroll
        for (int i = 0; i < 4; ++i) {
            const float s = (float)((gm + i) & (S_LEN - 1));
            #pragma unroll
            for (int j = 0; j < 4; ++j) {
                float sn, cs;
                sincosf(s * invf[j], &sn, &cs);
                float r = cre[i][j] * cs - cim[i][j] * sn;
                float m = cre[i][j] * sn + cim[i][j] * cs;
                cre[i][j] = r; cim[i][j] = m;
            }
        }
    }

    if (EPI == 2) {
        #pragma unroll
        for (int i = 0; i < 4; ++i) {
            size_t off = ((size_t)(gm + i) * DMODEL + gn) * 2;
            float4 v0 = make_float4(cre[i][0], cim[i][0], cre[i][1], cim[i][1]);
            float4 v1 = make_float4(cre[i][2], cim[i][2], cre[i][3], cim[i][3]);
            *(float4*)(Cre + off)     = v0;
            *(float4*)(Cre + off + 4) = v1;
        }
    } else {
        #pragma unroll
        for (int i = 0; i < 4; ++i) {
            size_t off = (size_t)(gm + i) * DMODEL + gn;
            *(float4*)(Cre + off) = make_float4(cre[i][0], cre[i][1], cre[i][2], cre[i][3]);
            *(float4*)(Cim + off) = make_float4(cim[i][0], cim[i][1], cim[i][2], cim[i][3]);
        }
    }
}

// ---------------------------------------------------------------------------
// Flash-style complex attention.
// grid: (S/64, B*H); block 256. Per block: 64 query rows, loop 32-key chunks.
// scores = Q * conj(K) / 8 ; probs = softmax(Re) ; phase = exp(i*Im)
// O = sum probs*phase*V  (online softmax, divide by l at end)
// ---------------------------------------------------------------------------
__global__ __launch_bounds__(256)
void flash_attn(const float* __restrict__ Qre, const float* __restrict__ Qim,
                const float* __restrict__ Kre, const float* __restrict__ Kim,
                const float* __restrict__ Vre, const float* __restrict__ Vim,
                float* __restrict__ Ore, float* __restrict__ Oim)
{
    __shared__ float Qt_re[64][64], Qt_im[64][64];   // [d][row]
    __shared__ float Kt_re[64][32], Kt_im[64][32];   // [d][key]
    __shared__ float Vs_re[32][64], Vs_im[32][64];   // [key][d]
    __shared__ float aT_re[32][64], aT_im[32][64];   // [key][row]

    const int tid = threadIdx.x;
    const int tx  = tid & 15;
    const int ty  = tid >> 4;
    const int q0  = blockIdx.x * 64;
    const int b   = blockIdx.y >> 4;
    const int h   = blockIdx.y & 15;
    const int colOff = h * DH;

    // ---- stage Q tile transposed [d][row] ----
    #pragma unroll
    for (int r = 0; r < 4; ++r) {
        int f   = tid + 256 * r;        // 0..1023
        int row = f >> 4;               // 0..63
        int dq  = (f & 15) << 2;        // 0..60
        size_t off = (size_t)(b * S_LEN + q0 + row) * DMODEL + colOff + dq;
        float4 qr = *(const float4*)(Qre + off);
        float4 qi = *(const float4*)(Qim + off);
        Qt_re[dq+0][row]=qr.x; Qt_re[dq+1][row]=qr.y; Qt_re[dq+2][row]=qr.z; Qt_re[dq+3][row]=qr.w;
        Qt_im[dq+0][row]=qi.x; Qt_im[dq+1][row]=qi.y; Qt_im[dq+2][row]=qi.z; Qt_im[dq+3][row]=qi.w;
    }

    float ore[4][4] = {{0.f}}, oim[4][4] = {{0.f}};
    float mrow[4], lrow[4];
    #pragma unroll
    for (int i = 0; i < 4; ++i) { mrow[i] = -INFINITY; lrow[i] = 0.f; }

    for (int t0 = 0; t0 < S_LEN; t0 += 32) {
        __syncthreads();   // Q staged (first iter) / previous PV + aT reads done
        // ---- stage K (transposed [d][key]) and V ([key][d]) ----
        #pragma unroll
        for (int r = 0; r < 2; ++r) {
            int f   = tid + 256 * r;    // 0..511
            int key = f >> 4;           // 0..31
            int dq  = (f & 15) << 2;
            size_t off = (size_t)(b * S_LEN + t0 + key) * DMODEL + colOff + dq;
            float4 kr = *(const float4*)(Kre + off);
            float4 ki = *(const float4*)(Kim + off);
            Kt_re[dq+0][key]=kr.x; Kt_re[dq+1][key]=kr.y; Kt_re[dq+2][key]=kr.z; Kt_re[dq+3][key]=kr.w;
            Kt_im[dq+0][key]=ki.x; Kt_im[dq+1][key]=ki.y; Kt_im[dq+2][key]=ki.z; Kt_im[dq+3][key]=ki.w;
            float4 vr = *(const float4*)(Vre + off);
            float4 vi = *(const float4*)(Vim + off);
            *(float4*)&Vs_re[key][dq] = vr;
            *(float4*)&Vs_im[key][dq] = vi;
        }
        __syncthreads();

        // ---- QK^H: 4 rows x 2 cols per thread ----
        const int c0 = tx << 1;
        float sre[4][2] = {{0.f}}, sim[4][2] = {{0.f}};
        #pragma unroll 16
        for (int k = 0; k < 64; ++k) {
            float4 q4r = *(const float4*)&Qt_re[k][ty<<2];
            float4 q4i = *(const float4*)&Qt_im[k][ty<<2];
            float2 k2r = *(const float2*)&Kt_re[k][c0];
            float2 k2i = *(const float2*)&Kt_im[k][c0];
            const float qr[4]={q4r.x,q4r.y,q4r.z,q4r.w};
            const float qi[4]={q4i.x,q4i.y,q4i.z,q4i.w};
            const float kr[2]={k2r.x,k2r.y};
            const float ki[2]={k2i.x,k2i.y};
            #pragma unroll
            for (int i = 0; i < 4; ++i)
                #pragma unroll
                for (int j = 0; j < 2; ++j) {
                    // q * conj(k)
                    sre[i][j] = fmaf(qr[i], kr[j], fmaf( qi[i], ki[j], sre[i][j]));
                    sim[i][j] = fmaf(qi[i], kr[j], fmaf(-qr[i], ki[j], sim[i][j]));
                }
        }

        // ---- online softmax stats + write probs*phase tile ----
        float esc[4];
        #pragma unroll
        for (int i = 0; i < 4; ++i) {
            float s0 = sre[i][0] * 0.125f, s1 = sre[i][1] * 0.125f;
            float im0 = sim[i][0] * 0.125f, im1 = sim[i][1] * 0.125f;
            float tmax = fmaxf(s0, s1);
            #pragma unroll
            for (int m = 1; m < 16; m <<= 1) tmax = fmaxf(tmax, __shfl_xor(tmax, m, 16));
            float mnew = fmaxf(mrow[i], tmax);
            float p0 = expf(s0 - mnew);
            float p1 = expf(s1 - mnew);
            float psum = p0 + p1;
            #pragma unroll
            for (int m = 1; m < 16; m <<= 1) psum += __shfl_xor(psum, m, 16);
            esc[i]  = expf(mrow[i] - mnew);
            lrow[i] = lrow[i] * esc[i] + psum;
            mrow[i] = mnew;
            float sn0, cs0, sn1, cs1;
            sincosf(im0, &sn0, &cs0);
            sincosf(im1, &sn1, &cs1);
            const int row = (ty << 2) + i;
            aT_re[c0+0][row] = p0 * cs0;  aT_im[c0+0][row] = p0 * sn0;
            aT_re[c0+1][row] = p1 * cs1;  aT_im[c0+1][row] = p1 * sn1;
        }
        // rescale accumulated O
        #pragma unroll
        for (int i = 0; i < 4; ++i)
            #pragma unroll
            for (int j = 0; j < 4; ++j) { ore[i][j] *= esc[i]; oim[i][j] *= esc[i]; }
        __syncthreads();

        // ---- PV: 4 rows x 4 d-cols per thread ----
        const int d0 = tx << 2;
        #pragma unroll 8
        for (int t = 0; t < 32; ++t) {
            float4 a4r = *(const float4*)&aT_re[t][ty<<2];
            float4 a4i = *(const float4*)&aT_im[t][ty<<2];
            float4 v4r = *(const float4*)&Vs_re[t][d0];
            float4 v4i = *(const float4*)&Vs_im[t][d0];
            const float ar[4]={a4r.x,a4r.y,a4r.z,a4r.w};
            const float ai[4]={a4i.x,a4i.y,a4i.z,a4i.w};
            const float vr[4]={v4r.x,v4r.y,v4r.z,v4r.w};
            const float vi[4]={v4i.x,v4i.y,v4i.z,v4i.w};
            #pragma unroll
            for (int i = 0; i < 4; ++i)
                #pragma unroll
                for (int j = 0; j < 4; ++j) {
                    ore[i][j] = fmaf(ar[i], vr[j], fmaf(-ai[i], vi[j], ore[i][j]));
                    oim[i][j] = fmaf(ar[i], vi[j], fmaf( ai[i], vr[j], oim[i][j]));
                }
        }
    }

    // ---- normalize + store ----
    const int d0 = tx << 2;
    #pragma unroll
    for (int i = 0; i < 4; ++i) {
        float inv = 1.f / lrow[i];
        size_t off = (size_t)(b * S_LEN + q0 + (ty<<2) + i) * DMODEL + colOff + d0;
        *(float4*)(Ore + off) = make_float4(ore[i][0]*inv, ore[i][1]*inv, ore[i][2]*inv, ore[i][3]*inv);
        *(float4*)(Oim + off) = make_float4(oim[i][0]*inv, oim[i][1]*inv, oim[i][2]*inv, oim[i][3]*inv);
    }
}

// ---------------------------------------------------------------------------
extern "C" void kernel_launch(void* const* d_in, const int* in_sizes, int n_in,
                              void* d_out, int out_size, void* d_ws, size_t ws_size,
                              hipStream_t stream)
{
    (void)in_sizes; (void)n_in; (void)out_size; (void)ws_size;
    const float* x_re  = (const float*)d_in[0];
    const float* x_im  = (const float*)d_in[1];
    const float* wq_re = (const float*)d_in[2];
    const float* wq_im = (const float*)d_in[3];
    const float* wk_re = (const float*)d_in[4];
    const float* wk_im = (const float*)d_in[5];
    const float* wv_re = (const float*)d_in[6];
    const float* wv_im = (const float*)d_in[7];
    const float* wo_re = (const float*)d_in[8];
    const float* wo_im = (const float*)d_in[9];
    float* out = (float*)d_out;

    float* ws = (float*)d_ws;
    const size_t NE = (size_t)2 * S_LEN * DMODEL;   // 2,097,152 elems per array
    float* Qre = ws + 0 * NE;  float* Qim = ws + 1 * NE;
    float* Kre = ws + 2 * NE;  float* Kim = ws + 3 * NE;
    float* Vre = ws + 4 * NE;  float* Vim = ws + 5 * NE;
    // Attention output aliases Q: each attn block reads its Q tile (global)
    // exactly once at kernel start and writes the same (rows x head-slice)
    // region only at the very end; no other block touches that region.
    float* Ore = Qre;          float* Oim = Qim;

    dim3 gGemm(2048 / 64, 1024 / 64);   // (32, 16)
    cgemm_nt<1><<<gGemm, 256, 0, stream>>>(x_re, x_im, wq_re, wq_im, Qre, Qim);
    cgemm_nt<1><<<gGemm, 256, 0, stream>>>(x_re, x_im, wk_re, wk_im, Kre, Kim);
    cgemm_nt<0><<<gGemm, 256, 0, stream>>>(x_re, x_im, wv_re, wv_im, Vre, Vim);

    flash_attn<<<dim3(S_LEN / 64, 32), 256, 0, stream>>>(Qre, Qim, Kre, Kim, Vre, Vim, Ore, Oim);

    cgemm_nt<2><<<gGemm, 256, 0, stream>>>(Ore, Oim, wo_re, wo_im, out, nullptr);
}

// Round 2
// 1276.771 us; speedup vs baseline: 1.0793x; 1.0793x over previous
//
#include <hip/hip_runtime.h>
#include <math.h>

#define S_LEN  1024
#define DMODEL 1024
#define DH     64

// ---------------------------------------------------------------------------
// Complex GEMM: C[M,N] = A[M,K] * B[N,K]^T  (both row-major, K contiguous)
// M = 2048, N = K = 1024. Tile 64x64, 256 threads, 4x4 complex per thread.
// T14 reg-prefetch: next K-chunk loaded to regs during compute.
// EPI: 0 = store Cre/Cim arrays
//      1 = apply RoPE rotor (s = row % S_LEN, k = col & 63) then store arrays
//      2 = store interleaved (re,im) pairs into Cre (the final output)
// ---------------------------------------------------------------------------
template<int EPI>
__global__ __launch_bounds__(256)
void cgemm_nt(const float* __restrict__ Are, const float* __restrict__ Aim,
              const float* __restrict__ Bre, const float* __restrict__ Bim,
              float* __restrict__ Cre, float* __restrict__ Cim)
{
    __shared__ float At_re[16][64], At_im[16][64];
    __shared__ float Bt_re[16][64], Bt_im[16][64];

    const int tid = threadIdx.x;
    const int tx  = tid & 15;       // col group: 4 cols
    const int ty  = tid >> 4;       // row group: 4 rows
    const int m0  = blockIdx.x * 64;
    const int n0  = blockIdx.y * 64;

    const int lm = tid >> 2;          // staging row 0..63
    const int lk = (tid & 3) << 2;    // staging k offset 0,4,8,12

    float cre[4][4] = {{0.f}}, cim[4][4] = {{0.f}};

    const size_t aBase = (size_t)(m0 + lm) * DMODEL + lk;
    const size_t bBase = (size_t)(n0 + lm) * DMODEL + lk;

    // prefetch k0 = 0
    float4 par = *(const float4*)(Are + aBase);
    float4 pai = *(const float4*)(Aim + aBase);
    float4 pbr = *(const float4*)(Bre + bBase);
    float4 pbi = *(const float4*)(Bim + bBase);

    for (int k0 = 0; k0 < DMODEL; k0 += 16) {
        __syncthreads();
        At_re[lk+0][lm]=par.x; At_re[lk+1][lm]=par.y; At_re[lk+2][lm]=par.z; At_re[lk+3][lm]=par.w;
        At_im[lk+0][lm]=pai.x; At_im[lk+1][lm]=pai.y; At_im[lk+2][lm]=pai.z; At_im[lk+3][lm]=pai.w;
        Bt_re[lk+0][lm]=pbr.x; Bt_re[lk+1][lm]=pbr.y; Bt_re[lk+2][lm]=pbr.z; Bt_re[lk+3][lm]=pbr.w;
        Bt_im[lk+0][lm]=pbi.x; Bt_im[lk+1][lm]=pbi.y; Bt_im[lk+2][lm]=pbi.z; Bt_im[lk+3][lm]=pbi.w;
        if (k0 + 16 < DMODEL) {
            par = *(const float4*)(Are + aBase + k0 + 16);
            pai = *(const float4*)(Aim + aBase + k0 + 16);
            pbr = *(const float4*)(Bre + bBase + k0 + 16);
            pbi = *(const float4*)(Bim + bBase + k0 + 16);
        }
        __syncthreads();

        #pragma unroll
        for (int k = 0; k < 16; ++k) {
            float4 q4r = *(const float4*)&At_re[k][ty<<2];
            float4 q4i = *(const float4*)&At_im[k][ty<<2];
            float4 w4r = *(const float4*)&Bt_re[k][tx<<2];
            float4 w4i = *(const float4*)&Bt_im[k][tx<<2];
            const float ar[4]={q4r.x,q4r.y,q4r.z,q4r.w};
            const float ai[4]={q4i.x,q4i.y,q4i.z,q4i.w};
            const float br[4]={w4r.x,w4r.y,w4r.z,w4r.w};
            const float bi[4]={w4i.x,w4i.y,w4i.z,w4i.w};
            #pragma unroll
            for (int i = 0; i < 4; ++i)
                #pragma unroll
                for (int j = 0; j < 4; ++j) {
                    cre[i][j] = fmaf(ar[i], br[j], fmaf(-ai[i], bi[j], cre[i][j]));
                    cim[i][j] = fmaf(ar[i], bi[j], fmaf( ai[i], br[j], cim[i][j]));
                }
        }
    }

    const int gm = m0 + (ty << 2);
    const int gn = n0 + (tx << 2);

    if (EPI == 1) {
        // RoPE rotor: angle = (row % S) * 10000^(-(col&63)/64)
        float invf[4];
        #pragma unroll
        for (int j = 0; j < 4; ++j)
            invf[j] = __expf(-(float)((gn + j) & 63) * 0.14391157f); // ln(1e4)/64
        #pragma unroll
        for (int i = 0; i < 4; ++i) {
            const float s = (float)((gm + i) & (S_LEN - 1));
            #pragma unroll
            for (int j = 0; j < 4; ++j) {
                float sn, cs;
                __sincosf(s * invf[j], &sn, &cs);
                float r = cre[i][j] * cs - cim[i][j] * sn;
                float m = cre[i][j] * sn + cim[i][j] * cs;
                cre[i][j] = r; cim[i][j] = m;
            }
        }
    }

    if (EPI == 2) {
        #pragma unroll
        for (int i = 0; i < 4; ++i) {
            size_t off = ((size_t)(gm + i) * DMODEL + gn) * 2;
            float4 v0 = make_float4(cre[i][0], cim[i][0], cre[i][1], cim[i][1]);
            float4 v1 = make_float4(cre[i][2], cim[i][2], cre[i][3], cim[i][3]);
            *(float4*)(Cre + off)     = v0;
            *(float4*)(Cre + off + 4) = v1;
        }
    } else {
        #pragma unroll
        for (int i = 0; i < 4; ++i) {
            size_t off = (size_t)(gm + i) * DMODEL + gn;
            *(float4*)(Cre + off) = make_float4(cre[i][0], cre[i][1], cre[i][2], cre[i][3]);
            *(float4*)(Cim + off) = make_float4(cim[i][0], cim[i][1], cim[i][2], cim[i][3]);
        }
    }
}

// ---------------------------------------------------------------------------
// Flash-style complex attention, v2.
// grid: (S/64, B*H); block 256. 64 query rows/block, 32-key chunks.
// XOR-swizzled transposed LDS tiles (conflict-free staging writes) +
// T14 reg-prefetch of next K/V chunk + native __expf/__sincosf.
// Swizzles (all bijective, verified):
//   Qt: elem (d,row) at Qt[d][row ^ (((d>>2)&7)<<2)]
//   Kt: elem (d,key) at Kt[d][key ^ (((d>>2)&15)<<1)]
//   aT: elem (key,row) at aT[key][row ^ ((key&7)<<2)]
// ---------------------------------------------------------------------------
__global__ __launch_bounds__(256)
void flash_attn(const float* __restrict__ Qre, const float* __restrict__ Qim,
                const float* __restrict__ Kre, const float* __restrict__ Kim,
                const float* __restrict__ Vre, const float* __restrict__ Vim,
                float* __restrict__ Ore, float* __restrict__ Oim)
{
    __shared__ float Qt_re[64][64], Qt_im[64][64];   // [d][row swz]
    __shared__ float Kt_re[64][32], Kt_im[64][32];   // [d][key swz]
    __shared__ float Vs_re[32][64], Vs_im[32][64];   // [key][d] natural
    __shared__ float aT_re[32][64], aT_im[32][64];   // [key][row swz]

    const int tid = threadIdx.x;
    const int tx  = tid & 15;
    const int ty  = tid >> 4;
    const int q0  = blockIdx.x * 64;
    const int b   = blockIdx.y >> 4;
    const int h   = blockIdx.y & 15;
    const int colOff = h * DH;

    // ---- stage Q tile transposed+swizzled, pre-scaled by 1/sqrt(Dh) ----
    #pragma unroll
    for (int r = 0; r < 4; ++r) {
        int f   = tid + 256 * r;        // 0..1023
        int row = f >> 4;               // 0..63
        int dq  = (f & 15) << 2;        // 0..60
        size_t off = (size_t)(b * S_LEN + q0 + row) * DMODEL + colOff + dq;
        float4 qr = *(const float4*)(Qre + off);
        float4 qi = *(const float4*)(Qim + off);
        int sw = row ^ ((((dq >> 2) & 7)) << 2);
        Qt_re[dq+0][sw]=qr.x*0.125f; Qt_re[dq+1][sw]=qr.y*0.125f; Qt_re[dq+2][sw]=qr.z*0.125f; Qt_re[dq+3][sw]=qr.w*0.125f;
        Qt_im[dq+0][sw]=qi.x*0.125f; Qt_im[dq+1][sw]=qi.y*0.125f; Qt_im[dq+2][sw]=qi.z*0.125f; Qt_im[dq+3][sw]=qi.w*0.125f;
    }

    float ore[4][4] = {{0.f}}, oim[4][4] = {{0.f}};
    float mrow[4], lrow[4];
    #pragma unroll
    for (int i = 0; i < 4; ++i) { mrow[i] = -INFINITY; lrow[i] = 0.f; }

    // ---- prefetch K/V chunk 0 into registers ----
    float4 pkr[2], pki[2], pvr[2], pvi[2];
    #pragma unroll
    for (int r = 0; r < 2; ++r) {
        int f   = tid + 256 * r;
        int key = f >> 4;
        int dq  = (f & 15) << 2;
        size_t off = (size_t)(b * S_LEN + key) * DMODEL + colOff + dq;
        pkr[r] = *(const float4*)(Kre + off);
        pki[r] = *(const float4*)(Kim + off);
        pvr[r] = *(const float4*)(Vre + off);
        pvi[r] = *(const float4*)(Vim + off);
    }

    for (int it = 0; it < S_LEN / 32; ++it) {
        __syncthreads();   // Q staged (it=0) / prior Kt,Vs,aT reads done
        // ---- write staged K (swizzled) and V (natural) from regs ----
        #pragma unroll
        for (int r = 0; r < 2; ++r) {
            int f   = tid + 256 * r;
            int key = f >> 4;
            int dq  = (f & 15) << 2;
            int swk = key ^ ((((dq >> 2) & 15)) << 1);
            Kt_re[dq+0][swk]=pkr[r].x; Kt_re[dq+1][swk]=pkr[r].y; Kt_re[dq+2][swk]=pkr[r].z; Kt_re[dq+3][swk]=pkr[r].w;
            Kt_im[dq+0][swk]=pki[r].x; Kt_im[dq+1][swk]=pki[r].y; Kt_im[dq+2][swk]=pki[r].z; Kt_im[dq+3][swk]=pki[r].w;
            *(float4*)&Vs_re[key][dq] = pvr[r];
            *(float4*)&Vs_im[key][dq] = pvi[r];
        }
        // ---- issue prefetch for next chunk (latency hides under compute) ----
        if (it + 1 < S_LEN / 32) {
            #pragma unroll
            for (int r = 0; r < 2; ++r) {
                int f   = tid + 256 * r;
                int key = f >> 4;
                int dq  = (f & 15) << 2;
                size_t off = (size_t)(b * S_LEN + (it+1)*32 + key) * DMODEL + colOff + dq;
                pkr[r] = *(const float4*)(Kre + off);
                pki[r] = *(const float4*)(Kim + off);
                pvr[r] = *(const float4*)(Vre + off);
                pvi[r] = *(const float4*)(Vim + off);
            }
        }
        __syncthreads();

        // ---- QK^H: 4 rows x 2 keys per thread ----
        const int c0 = tx << 1;
        float sre[4][2] = {{0.f}}, sim[4][2] = {{0.f}};
        #pragma unroll 8
        for (int k = 0; k < 64; ++k) {
            const int qb = (ty << 2) ^ ((((k >> 2) & 7)) << 2);
            const int kb = c0 ^ ((((k >> 2) & 15)) << 1);
            float4 q4r = *(const float4*)&Qt_re[k][qb];
            float4 q4i = *(const float4*)&Qt_im[k][qb];
            float2 k2r = *(const float2*)&Kt_re[k][kb];
            float2 k2i = *(const float2*)&Kt_im[k][kb];
            const float qr[4]={q4r.x,q4r.y,q4r.z,q4r.w};
            const float qi[4]={q4i.x,q4i.y,q4i.z,q4i.w};
            const float kr[2]={k2r.x,k2r.y};
            const float ki[2]={k2i.x,k2i.y};
            #pragma unroll
            for (int i = 0; i < 4; ++i)
                #pragma unroll
                for (int j = 0; j < 2; ++j) {
                    // q * conj(k), pre-scaled
                    sre[i][j] = fmaf(qr[i], kr[j], fmaf( qi[i], ki[j], sre[i][j]));
                    sim[i][j] = fmaf(qi[i], kr[j], fmaf(-qr[i], ki[j], sim[i][j]));
                }
        }

        // ---- online softmax + rotor; write probs*phase (swizzled aT) ----
        const int c1 = c0 + 1;
        const int sa0 = (c0 & 7) << 2;
        const int sa1 = (c1 & 7) << 2;
        float esc[4];
        #pragma unroll
        for (int i = 0; i < 4; ++i) {
            float s0 = sre[i][0], s1 = sre[i][1];
            float tmax = fmaxf(s0, s1);
            #pragma unroll
            for (int m = 1; m < 16; m <<= 1) tmax = fmaxf(tmax, __shfl_xor(tmax, m, 16));
            float mnew = fmaxf(mrow[i], tmax);
            float p0 = __expf(s0 - mnew);
            float p1 = __expf(s1 - mnew);
            float psum = p0 + p1;
            #pragma unroll
            for (int m = 1; m < 16; m <<= 1) psum += __shfl_xor(psum, m, 16);
            esc[i]  = __expf(mrow[i] - mnew);
            lrow[i] = lrow[i] * esc[i] + psum;
            mrow[i] = mnew;
            float sn0, cs0, sn1, cs1;
            __sincosf(sim[i][0], &sn0, &cs0);
            __sincosf(sim[i][1], &sn1, &cs1);
            const int row = (ty << 2) + i;
            aT_re[c0][row ^ sa0] = p0 * cs0;  aT_im[c0][row ^ sa0] = p0 * sn0;
            aT_re[c1][row ^ sa1] = p1 * cs1;  aT_im[c1][row ^ sa1] = p1 * sn1;
        }
        // rescale accumulated O
        #pragma unroll
        for (int i = 0; i < 4; ++i)
            #pragma unroll
            for (int j = 0; j < 4; ++j) { ore[i][j] *= esc[i]; oim[i][j] *= esc[i]; }
        __syncthreads();

        // ---- PV: 4 rows x 4 d-cols per thread ----
        const int d0 = tx << 2;
        #pragma unroll 8
        for (int t = 0; t < 32; ++t) {
            const int ab = (ty << 2) ^ ((t & 7) << 2);
            float4 a4r = *(const float4*)&aT_re[t][ab];
            float4 a4i = *(const float4*)&aT_im[t][ab];
            float4 v4r = *(const float4*)&Vs_re[t][d0];
            float4 v4i = *(const float4*)&Vs_im[t][d0];
            const float ar[4]={a4r.x,a4r.y,a4r.z,a4r.w};
            const float ai[4]={a4i.x,a4i.y,a4i.z,a4i.w};
            const float vr[4]={v4r.x,v4r.y,v4r.z,v4r.w};
            const float vi[4]={v4i.x,v4i.y,v4i.z,v4i.w};
            #pragma unroll
            for (int i = 0; i < 4; ++i)
                #pragma unroll
                for (int j = 0; j < 4; ++j) {
                    ore[i][j] = fmaf(ar[i], vr[j], fmaf(-ai[i], vi[j], ore[i][j]));
                    oim[i][j] = fmaf(ar[i], vi[j], fmaf( ai[i], vr[j], oim[i][j]));
                }
        }
    }

    // ---- normalize + store ----
    const int d0 = tx << 2;
    #pragma unroll
    for (int i = 0; i < 4; ++i) {
        float inv = 1.f / lrow[i];
        size_t off = (size_t)(b * S_LEN + q0 + (ty<<2) + i) * DMODEL + colOff + d0;
        *(float4*)(Ore + off) = make_float4(ore[i][0]*inv, ore[i][1]*inv, ore[i][2]*inv, ore[i][3]*inv);
        *(float4*)(Oim + off) = make_float4(oim[i][0]*inv, oim[i][1]*inv, oim[i][2]*inv, oim[i][3]*inv);
    }
}

// ---------------------------------------------------------------------------
extern "C" void kernel_launch(void* const* d_in, const int* in_sizes, int n_in,
                              void* d_out, int out_size, void* d_ws, size_t ws_size,
                              hipStream_t stream)
{
    (void)in_sizes; (void)n_in; (void)out_size; (void)ws_size;
    const float* x_re  = (const float*)d_in[0];
    const float* x_im  = (const float*)d_in[1];
    const float* wq_re = (const float*)d_in[2];
    const float* wq_im = (const float*)d_in[3];
    const float* wk_re = (const float*)d_in[4];
    const float* wk_im = (const float*)d_in[5];
    const float* wv_re = (const float*)d_in[6];
    const float* wv_im = (const float*)d_in[7];
    const float* wo_re = (const float*)d_in[8];
    const float* wo_im = (const float*)d_in[9];
    float* out = (float*)d_out;

    float* ws = (float*)d_ws;
    const size_t NE = (size_t)2 * S_LEN * DMODEL;   // 2,097,152 elems per array
    float* Qre = ws + 0 * NE;  float* Qim = ws + 1 * NE;
    float* Kre = ws + 2 * NE;  float* Kim = ws + 3 * NE;
    float* Vre = ws + 4 * NE;  float* Vim = ws + 5 * NE;
    // Attention output aliases Q: each attn block reads its Q tile (global)
    // exactly once at kernel start and writes the same (rows x head-slice)
    // region only at the very end; no other block touches that region.
    float* Ore = Qre;          float* Oim = Qim;

    dim3 gGemm(2048 / 64, 1024 / 64);   // (32, 16)
    cgemm_nt<1><<<gGemm, 256, 0, stream>>>(x_re, x_im, wq_re, wq_im, Qre, Qim);
    cgemm_nt<1><<<gGemm, 256, 0, stream>>>(x_re, x_im, wk_re, wk_im, Kre, Kim);
    cgemm_nt<0><<<gGemm, 256, 0, stream>>>(x_re, x_im, wv_re, wv_im, Vre, Vim);

    flash_attn<<<dim3(S_LEN / 64, 32), 256, 0, stream>>>(Qre, Qim, Kre, Kim, Vre, Vim, Ore, Oim);

    cgemm_nt<2><<<gGemm, 256, 0, stream>>>(Ore, Oim, wo_re, wo_im, out, nullptr);
}

// Round 3
// 704.393 us; speedup vs baseline: 1.9564x; 1.8126x over previous
//
#include <hip/hip_runtime.h>
#include <math.h>

#define S_LEN  1024
#define DMODEL 1024
#define DH     64

typedef float  f4     __attribute__((ext_vector_type(4)));
typedef float  f32x4  __attribute__((ext_vector_type(4)));
typedef __bf16 bf16x8 __attribute__((ext_vector_type(8)));
typedef unsigned int u32x4 __attribute__((ext_vector_type(4)));

__device__ __forceinline__ bf16x8 neg8(bf16x8 v) {
    u32x4 u;
    __builtin_memcpy(&u, &v, 16);
    u ^= 0x80008000u;
    bf16x8 r;
    __builtin_memcpy(&r, &u, 16);
    return r;
}

// ---------------------------------------------------------------------------
// Split fp32 (re,im) into bf16 hi/lo planes: dst + {0,1,2,3}*plane = hr,lr,hi,li
// ---------------------------------------------------------------------------
__global__ __launch_bounds__(256)
void split_bf16(const float* __restrict__ re, const float* __restrict__ im,
                __bf16* __restrict__ dst, size_t plane, int n8)
{
    int idx = blockIdx.x * 256 + threadIdx.x;
    if (idx >= n8) return;
    f4 r0 = ((const f4*)re)[idx*2];
    f4 r1 = ((const f4*)re)[idx*2+1];
    f4 i0 = ((const f4*)im)[idx*2];
    f4 i1 = ((const f4*)im)[idx*2+1];
    float rr[8] = {r0.x,r0.y,r0.z,r0.w,r1.x,r1.y,r1.z,r1.w};
    float ii[8] = {i0.x,i0.y,i0.z,i0.w,i1.x,i1.y,i1.z,i1.w};
    bf16x8 hr, lr, hi, li;
    #pragma unroll
    for (int j = 0; j < 8; ++j) {
        __bf16 h = (__bf16)rr[j];
        hr[j] = h; lr[j] = (__bf16)(rr[j] - (float)h);
        __bf16 g = (__bf16)ii[j];
        hi[j] = g; li[j] = (__bf16)(ii[j] - (float)g);
    }
    ((bf16x8*)(dst + 0*plane))[idx] = hr;
    ((bf16x8*)(dst + 1*plane))[idx] = lr;
    ((bf16x8*)(dst + 2*plane))[idx] = hi;
    ((bf16x8*)(dst + 3*plane))[idx] = li;
}

// ---------------------------------------------------------------------------
// Split-bf16 complex GEMM via MFMA: C[M=2048, N] = A[2048,1024] * B[N,1024]^T
// A,B given as 4 bf16 planes each: {hi_re, lo_re, hi_im, lo_im}.
// Re = hr*whr + hr*wlr + lr*whr - hi*whi - hi*wli - li*whi
// Im = hr*whi + hr*wli + lr*whi + hi*whr + hi*wlr + li*whr
// BM=128 BN=64 BK=32, 256 threads (4 waves, 2x2), wave tile 64x32.
// EPI 1: planar store to Q/K/V (seg = n0>>10), RoPE rotor for seg<2.
// EPI 2: interleaved (re,im) store to q_re.
// ---------------------------------------------------------------------------
template<int EPI>
__global__ __launch_bounds__(256, 2)
void cgemm_mfma(const __bf16* __restrict__ A, const __bf16* __restrict__ B,
                size_t bPlane,
                float* __restrict__ q_re, float* __restrict__ q_im,
                float* __restrict__ k_re, float* __restrict__ k_im,
                float* __restrict__ v_re, float* __restrict__ v_im)
{
    __shared__ __bf16 As[4*128*32];
    __shared__ __bf16 Bs[4*64*32];

    const int tid  = threadIdx.x;
    const int lane = tid & 63;
    const int wid  = tid >> 6;
    const int wm   = wid >> 1, wn = wid & 1;
    const int lrow = lane & 15, lk = lane >> 4;
    const int m0   = blockIdx.x * 128;
    const int n0   = blockIdx.y * 64;
    const size_t aPlane = (size_t)2048 * 1024;

    f32x4 accRe[4][2], accIm[4][2];
    #pragma unroll
    for (int i = 0; i < 4; ++i)
        #pragma unroll
        for (int j = 0; j < 2; ++j) {
            accRe[i][j] = (f32x4){0.f,0.f,0.f,0.f};
            accIm[i][j] = (f32x4){0.f,0.f,0.f,0.f};
        }

    f4 prA[8], prB[4];
    // prefetch k0 = 0
    #pragma unroll
    for (int i = 0; i < 8; ++i) {
        int c = tid + 256*i;
        int mat = c >> 9, row = (c >> 2) & 127, ks = c & 3;
        prA[i] = *(const f4*)(A + (size_t)mat*aPlane + (size_t)(m0+row)*1024 + ks*8);
    }
    #pragma unroll
    for (int i = 0; i < 4; ++i) {
        int c = tid + 256*i;
        int mat = c >> 8, row = (c >> 2) & 63, ks = c & 3;
        prB[i] = *(const f4*)(B + (size_t)mat*bPlane + (size_t)(n0+row)*1024 + ks*8);
    }

    const int phys = (lk ^ ((lrow >> 1) & 3)) << 3;

    for (int it = 0; it < 32; ++it) {
        __syncthreads();
        // ---- write staged chunks to swizzled LDS ----
        #pragma unroll
        for (int i = 0; i < 8; ++i) {
            int c = tid + 256*i;
            int mat = c >> 9, row = (c >> 2) & 127, ks = c & 3;
            int wp = (ks ^ ((row >> 1) & 3)) << 3;
            *(f4*)&As[(mat*128 + row)*32 + wp] = prA[i];
        }
        #pragma unroll
        for (int i = 0; i < 4; ++i) {
            int c = tid + 256*i;
            int mat = c >> 8, row = (c >> 2) & 63, ks = c & 3;
            int wp = (ks ^ ((row >> 1) & 3)) << 3;
            *(f4*)&Bs[(mat*64 + row)*32 + wp] = prB[i];
        }
        __syncthreads();
        // ---- issue next-tile prefetch (latency hides under MFMA below) ----
        if (it < 31) {
            const int k0 = (it + 1) * 32;
            #pragma unroll
            for (int i = 0; i < 8; ++i) {
                int c = tid + 256*i;
                int mat = c >> 9, row = (c >> 2) & 127, ks = c & 3;
                prA[i] = *(const f4*)(A + (size_t)mat*aPlane + (size_t)(m0+row)*1024 + k0 + ks*8);
            }
            #pragma unroll
            for (int i = 0; i < 4; ++i) {
                int c = tid + 256*i;
                int mat = c >> 8, row = (c >> 2) & 63, ks = c & 3;
                prB[i] = *(const f4*)(B + (size_t)mat*bPlane + (size_t)(n0+row)*1024 + k0 + ks*8);
            }
        }
        // ---- compute: 96 MFMA per wave ----
        bf16x8 bw[2][4];
        #pragma unroll
        for (int nf = 0; nf < 2; ++nf)
            #pragma unroll
            for (int mat = 0; mat < 4; ++mat)
                bw[nf][mat] = *(const bf16x8*)&Bs[(mat*64 + wn*32 + nf*16 + lrow)*32 + phys];
        #pragma unroll
        for (int mf = 0; mf < 4; ++mf) {
            const int arow = wm*64 + mf*16 + lrow;
            bf16x8 xhr = *(const bf16x8*)&As[(0*128 + arow)*32 + phys];
            bf16x8 xlr = *(const bf16x8*)&As[(1*128 + arow)*32 + phys];
            bf16x8 xhi = *(const bf16x8*)&As[(2*128 + arow)*32 + phys];
            bf16x8 xli = *(const bf16x8*)&As[(3*128 + arow)*32 + phys];
            bf16x8 nhi = neg8(xhi), nli = neg8(xli);
            #pragma unroll
            for (int nf = 0; nf < 2; ++nf) {
                f32x4 r  = accRe[mf][nf];
                f32x4 m2 = accIm[mf][nf];
                r  = __builtin_amdgcn_mfma_f32_16x16x32_bf16(xhr, bw[nf][0], r, 0,0,0);
                r  = __builtin_amdgcn_mfma_f32_16x16x32_bf16(xhr, bw[nf][1], r, 0,0,0);
                r  = __builtin_amdgcn_mfma_f32_16x16x32_bf16(xlr, bw[nf][0], r, 0,0,0);
                r  = __builtin_amdgcn_mfma_f32_16x16x32_bf16(nhi, bw[nf][2], r, 0,0,0);
                r  = __builtin_amdgcn_mfma_f32_16x16x32_bf16(nhi, bw[nf][3], r, 0,0,0);
                r  = __builtin_amdgcn_mfma_f32_16x16x32_bf16(nli, bw[nf][2], r, 0,0,0);
                m2 = __builtin_amdgcn_mfma_f32_16x16x32_bf16(xhr, bw[nf][2], m2, 0,0,0);
                m2 = __builtin_amdgcn_mfma_f32_16x16x32_bf16(xhr, bw[nf][3], m2, 0,0,0);
                m2 = __builtin_amdgcn_mfma_f32_16x16x32_bf16(xlr, bw[nf][2], m2, 0,0,0);
                m2 = __builtin_amdgcn_mfma_f32_16x16x32_bf16(xhi, bw[nf][0], m2, 0,0,0);
                m2 = __builtin_amdgcn_mfma_f32_16x16x32_bf16(xhi, bw[nf][1], m2, 0,0,0);
                m2 = __builtin_amdgcn_mfma_f32_16x16x32_bf16(xli, bw[nf][0], m2, 0,0,0);
                accRe[mf][nf] = r; accIm[mf][nf] = m2;
            }
        }
    }

    // ---- epilogue: C/D layout col=lane&15, row=(lane>>4)*4+reg ----
    const int seg  = n0 >> 10;
    const int nloc = n0 & 1023;
    float* dre = q_re; float* dim_ = q_im;
    if (EPI == 1) {
        if (seg == 1)      { dre = k_re; dim_ = k_im; }
        else if (seg == 2) { dre = v_re; dim_ = v_im; }
    }
    #pragma unroll
    for (int mf = 0; mf < 4; ++mf) {
        #pragma unroll
        for (int nf = 0; nf < 2; ++nf) {
            const int colB = wn*32 + nf*16 + lrow;   // 0..63 == dh
            const int colG = nloc + colB;
            f32x4 r  = accRe[mf][nf];
            f32x4 m2 = accIm[mf][nf];
            float invf = 0.f;
            if (EPI == 1 && seg < 2) invf = __expf(-(float)colB * 0.14391157f); // ln(1e4)/64
            #pragma unroll
            for (int rg = 0; rg < 4; ++rg) {
                const int m = m0 + wm*64 + mf*16 + lk*4 + rg;
                float re = r[rg], im = m2[rg];
                if (EPI == 1) {
                    if (seg < 2) {
                        float sn, cs;
                        __sincosf((float)(m & (S_LEN-1)) * invf, &sn, &cs);
                        float t = re*cs - im*sn;
                        im = re*sn + im*cs; re = t;
                    }
                    size_t off = (size_t)m*1024 + colG;
                    dre[off] = re; dim_[off] = im;
                } else {
                    size_t off = ((size_t)m*1024 + colG)*2;
                    q_re[off] = re; q_re[off+1] = im;
                }
            }
        }
    }
}

// ---------------------------------------------------------------------------
// Flash-style complex attention (unchanged from round 2).
// ---------------------------------------------------------------------------
__global__ __launch_bounds__(256)
void flash_attn(const float* __restrict__ Qre, const float* __restrict__ Qim,
                const float* __restrict__ Kre, const float* __restrict__ Kim,
                const float* __restrict__ Vre, const float* __restrict__ Vim,
                float* __restrict__ Ore, float* __restrict__ Oim)
{
    __shared__ float Qt_re[64][64], Qt_im[64][64];   // [d][row swz]
    __shared__ float Kt_re[64][32], Kt_im[64][32];   // [d][key swz]
    __shared__ float Vs_re[32][64], Vs_im[32][64];   // [key][d] natural
    __shared__ float aT_re[32][64], aT_im[32][64];   // [key][row swz]

    const int tid = threadIdx.x;
    const int tx  = tid & 15;
    const int ty  = tid >> 4;
    const int q0  = blockIdx.x * 64;
    const int b   = blockIdx.y >> 4;
    const int h   = blockIdx.y & 15;
    const int colOff = h * DH;

    #pragma unroll
    for (int r = 0; r < 4; ++r) {
        int f   = tid + 256 * r;
        int row = f >> 4;
        int dq  = (f & 15) << 2;
        size_t off = (size_t)(b * S_LEN + q0 + row) * DMODEL + colOff + dq;
        float4 qr = *(const float4*)(Qre + off);
        float4 qi = *(const float4*)(Qim + off);
        int sw = row ^ ((((dq >> 2) & 7)) << 2);
        Qt_re[dq+0][sw]=qr.x*0.125f; Qt_re[dq+1][sw]=qr.y*0.125f; Qt_re[dq+2][sw]=qr.z*0.125f; Qt_re[dq+3][sw]=qr.w*0.125f;
        Qt_im[dq+0][sw]=qi.x*0.125f; Qt_im[dq+1][sw]=qi.y*0.125f; Qt_im[dq+2][sw]=qi.z*0.125f; Qt_im[dq+3][sw]=qi.w*0.125f;
    }

    float ore[4][4] = {{0.f}}, oim[4][4] = {{0.f}};
    float mrow[4], lrow[4];
    #pragma unroll
    for (int i = 0; i < 4; ++i) { mrow[i] = -INFINITY; lrow[i] = 0.f; }

    float4 pkr[2], pki[2], pvr[2], pvi[2];
    #pragma unroll
    for (int r = 0; r < 2; ++r) {
        int f   = tid + 256 * r;
        int key = f >> 4;
        int dq  = (f & 15) << 2;
        size_t off = (size_t)(b * S_LEN + key) * DMODEL + colOff + dq;
        pkr[r] = *(const float4*)(Kre + off);
        pki[r] = *(const float4*)(Kim + off);
        pvr[r] = *(const float4*)(Vre + off);
        pvi[r] = *(const float4*)(Vim + off);
    }

    for (int it = 0; it < S_LEN / 32; ++it) {
        __syncthreads();
        #pragma unroll
        for (int r = 0; r < 2; ++r) {
            int f   = tid + 256 * r;
            int key = f >> 4;
            int dq  = (f & 15) << 2;
            int swk = key ^ ((((dq >> 2) & 15)) << 1);
            Kt_re[dq+0][swk]=pkr[r].x; Kt_re[dq+1][swk]=pkr[r].y; Kt_re[dq+2][swk]=pkr[r].z; Kt_re[dq+3][swk]=pkr[r].w;
            Kt_im[dq+0][swk]=pki[r].x; Kt_im[dq+1][swk]=pki[r].y; Kt_im[dq+2][swk]=pki[r].z; Kt_im[dq+3][swk]=pki[r].w;
            *(float4*)&Vs_re[key][dq] = pvr[r];
            *(float4*)&Vs_im[key][dq] = pvi[r];
        }
        if (it + 1 < S_LEN / 32) {
            #pragma unroll
            for (int r = 0; r < 2; ++r) {
                int f   = tid + 256 * r;
                int key = f >> 4;
                int dq  = (f & 15) << 2;
                size_t off = (size_t)(b * S_LEN + (it+1)*32 + key) * DMODEL + colOff + dq;
                pkr[r] = *(const float4*)(Kre + off);
                pki[r] = *(const float4*)(Kim + off);
                pvr[r] = *(const float4*)(Vre + off);
                pvi[r] = *(const float4*)(Vim + off);
            }
        }
        __syncthreads();

        const int c0 = tx << 1;
        float sre[4][2] = {{0.f}}, sim[4][2] = {{0.f}};
        #pragma unroll 8
        for (int k = 0; k < 64; ++k) {
            const int qb = (ty << 2) ^ ((((k >> 2) & 7)) << 2);
            const int kb = c0 ^ ((((k >> 2) & 15)) << 1);
            float4 q4r = *(const float4*)&Qt_re[k][qb];
            float4 q4i = *(const float4*)&Qt_im[k][qb];
            float2 k2r = *(const float2*)&Kt_re[k][kb];
            float2 k2i = *(const float2*)&Kt_im[k][kb];
            const float qr[4]={q4r.x,q4r.y,q4r.z,q4r.w};
            const float qi[4]={q4i.x,q4i.y,q4i.z,q4i.w};
            const float kr[2]={k2r.x,k2r.y};
            const float ki[2]={k2i.x,k2i.y};
            #pragma unroll
            for (int i = 0; i < 4; ++i)
                #pragma unroll
                for (int j = 0; j < 2; ++j) {
                    sre[i][j] = fmaf(qr[i], kr[j], fmaf( qi[i], ki[j], sre[i][j]));
                    sim[i][j] = fmaf(qi[i], kr[j], fmaf(-qr[i], ki[j], sim[i][j]));
                }
        }

        const int c1 = c0 + 1;
        const int sa0 = (c0 & 7) << 2;
        const int sa1 = (c1 & 7) << 2;
        float esc[4];
        #pragma unroll
        for (int i = 0; i < 4; ++i) {
            float s0 = sre[i][0], s1 = sre[i][1];
            float tmax = fmaxf(s0, s1);
            #pragma unroll
            for (int m = 1; m < 16; m <<= 1) tmax = fmaxf(tmax, __shfl_xor(tmax, m, 16));
            float mnew = fmaxf(mrow[i], tmax);
            float p0 = __expf(s0 - mnew);
            float p1 = __expf(s1 - mnew);
            float psum = p0 + p1;
            #pragma unroll
            for (int m = 1; m < 16; m <<= 1) psum += __shfl_xor(psum, m, 16);
            esc[i]  = __expf(mrow[i] - mnew);
            lrow[i] = lrow[i] * esc[i] + psum;
            mrow[i] = mnew;
            float sn0, cs0, sn1, cs1;
            __sincosf(sim[i][0], &sn0, &cs0);
            __sincosf(sim[i][1], &sn1, &cs1);
            const int row = (ty << 2) + i;
            aT_re[c0][row ^ sa0] = p0 * cs0;  aT_im[c0][row ^ sa0] = p0 * sn0;
            aT_re[c1][row ^ sa1] = p1 * cs1;  aT_im[c1][row ^ sa1] = p1 * sn1;
        }
        #pragma unroll
        for (int i = 0; i < 4; ++i)
            #pragma unroll
            for (int j = 0; j < 4; ++j) { ore[i][j] *= esc[i]; oim[i][j] *= esc[i]; }
        __syncthreads();

        const int d0 = tx << 2;
        #pragma unroll 8
        for (int t = 0; t < 32; ++t) {
            const int ab = (ty << 2) ^ ((t & 7) << 2);
            float4 a4r = *(const float4*)&aT_re[t][ab];
            float4 a4i = *(const float4*)&aT_im[t][ab];
            float4 v4r = *(const float4*)&Vs_re[t][d0];
            float4 v4i = *(const float4*)&Vs_im[t][d0];
            const float ar[4]={a4r.x,a4r.y,a4r.z,a4r.w};
            const float ai[4]={a4i.x,a4i.y,a4i.z,a4i.w};
            const float vr[4]={v4r.x,v4r.y,v4r.z,v4r.w};
            const float vi[4]={v4i.x,v4i.y,v4i.z,v4i.w};
            #pragma unroll
            for (int i = 0; i < 4; ++i)
                #pragma unroll
                for (int j = 0; j < 4; ++j) {
                    ore[i][j] = fmaf(ar[i], vr[j], fmaf(-ai[i], vi[j], ore[i][j]));
                    oim[i][j] = fmaf(ar[i], vi[j], fmaf( ai[i], vr[j], oim[i][j]));
                }
        }
    }

    const int d0 = tx << 2;
    #pragma unroll
    for (int i = 0; i < 4; ++i) {
        float inv = 1.f / lrow[i];
        size_t off = (size_t)(b * S_LEN + q0 + (ty<<2) + i) * DMODEL + colOff + d0;
        *(float4*)(Ore + off) = make_float4(ore[i][0]*inv, ore[i][1]*inv, ore[i][2]*inv, ore[i][3]*inv);
        *(float4*)(Oim + off) = make_float4(oim[i][0]*inv, oim[i][1]*inv, oim[i][2]*inv, oim[i][3]*inv);
    }
}

// ---------------------------------------------------------------------------
extern "C" void kernel_launch(void* const* d_in, const int* in_sizes, int n_in,
                              void* d_out, int out_size, void* d_ws, size_t ws_size,
                              hipStream_t stream)
{
    (void)in_sizes; (void)n_in; (void)out_size; (void)ws_size;
    const float* x_re  = (const float*)d_in[0];
    const float* x_im  = (const float*)d_in[1];
    const float* wq_re = (const float*)d_in[2];
    const float* wq_im = (const float*)d_in[3];
    const float* wk_re = (const float*)d_in[4];
    const float* wk_im = (const float*)d_in[5];
    const float* wv_re = (const float*)d_in[6];
    const float* wv_im = (const float*)d_in[7];
    const float* wo_re = (const float*)d_in[8];
    const float* wo_im = (const float*)d_in[9];
    float* out = (float*)d_out;

    char* wsb = (char*)d_ws;
    const size_t MB = (size_t)1 << 20;
    float* Qre = (float*)(wsb +  0*MB);
    float* Qim = (float*)(wsb +  8*MB);
    float* Kre = (float*)(wsb + 16*MB);
    float* Kim = (float*)(wsb + 24*MB);
    float* Vre = (float*)(wsb + 32*MB);
    float* Vim = (float*)(wsb + 40*MB);
    __bf16* wo_s   = (__bf16*)(wsb + 48*MB);   // 4 planes x 1M
    __bf16* x_s    = (__bf16*)(wsb + 56*MB);   // 4 planes x 2M
    __bf16* o_s    = x_s;                      // reuse after QKV GEMM
    __bf16* wqkv_s = (__bf16*)(wsb + 72*MB);   // 4 planes x 3M

    const size_t P1M = (size_t)1024 * 1024;
    const size_t P2M = 2 * P1M;
    const size_t P3M = 3 * P1M;

    // splits
    split_bf16<<<1024, 256, 0, stream>>>(x_re, x_im, x_s, P2M, (int)(P2M/8));
    split_bf16<<< 512, 256, 0, stream>>>(wq_re, wq_im, wqkv_s,         P3M, (int)(P1M/8));
    split_bf16<<< 512, 256, 0, stream>>>(wk_re, wk_im, wqkv_s + P1M,   P3M, (int)(P1M/8));
    split_bf16<<< 512, 256, 0, stream>>>(wv_re, wv_im, wqkv_s + 2*P1M, P3M, (int)(P1M/8));
    split_bf16<<< 512, 256, 0, stream>>>(wo_re, wo_im, wo_s, P1M, (int)(P1M/8));

    // fused QKV projection + RoPE (MFMA)
    cgemm_mfma<1><<<dim3(16, 48), 256, 0, stream>>>(x_s, wqkv_s, P3M,
                                                    Qre, Qim, Kre, Kim, Vre, Vim);
    // attention (O aliases Q)
    flash_attn<<<dim3(16, 32), 256, 0, stream>>>(Qre, Qim, Kre, Kim, Vre, Vim, Qre, Qim);
    // split attention output, then O projection (MFMA) with interleaved store
    split_bf16<<<1024, 256, 0, stream>>>(Qre, Qim, o_s, P2M, (int)(P2M/8));
    cgemm_mfma<2><<<dim3(16, 16), 256, 0, stream>>>(o_s, wo_s, P1M,
                                                    out, nullptr, nullptr, nullptr, nullptr, nullptr);
}

// Round 4
// 332.637 us; speedup vs baseline: 4.1428x; 2.1176x over previous
//
#include <hip/hip_runtime.h>
#include <math.h>

#define S_LEN  1024
#define DMODEL 1024
#define DH     64

typedef float  f4     __attribute__((ext_vector_type(4)));
typedef float  f32x4  __attribute__((ext_vector_type(4)));
typedef __bf16 bf16x8 __attribute__((ext_vector_type(8)));
typedef unsigned int u32x4 __attribute__((ext_vector_type(4)));

__device__ __forceinline__ bf16x8 neg8(bf16x8 v) {
    u32x4 u;
    __builtin_memcpy(&u, &v, 16);
    u ^= 0x80008000u;
    bf16x8 r;
    __builtin_memcpy(&r, &u, 16);
    return r;
}

// ---------------------------------------------------------------------------
// Split fp32 (re,im) into bf16 hi/lo planes: dst + {0,1,2,3}*plane = hr,lr,hi,li
// ---------------------------------------------------------------------------
__global__ __launch_bounds__(256)
void split_bf16(const float* __restrict__ re, const float* __restrict__ im,
                __bf16* __restrict__ dst, size_t plane, int n8)
{
    int idx = blockIdx.x * 256 + threadIdx.x;
    if (idx >= n8) return;
    f4 r0 = ((const f4*)re)[idx*2];
    f4 r1 = ((const f4*)re)[idx*2+1];
    f4 i0 = ((const f4*)im)[idx*2];
    f4 i1 = ((const f4*)im)[idx*2+1];
    float rr[8] = {r0.x,r0.y,r0.z,r0.w,r1.x,r1.y,r1.z,r1.w};
    float ii[8] = {i0.x,i0.y,i0.z,i0.w,i1.x,i1.y,i1.z,i1.w};
    bf16x8 hr, lr, hi, li;
    #pragma unroll
    for (int j = 0; j < 8; ++j) {
        __bf16 h = (__bf16)rr[j];
        hr[j] = h; lr[j] = (__bf16)(rr[j] - (float)h);
        __bf16 g = (__bf16)ii[j];
        hi[j] = g; li[j] = (__bf16)(ii[j] - (float)g);
    }
    ((bf16x8*)(dst + 0*plane))[idx] = hr;
    ((bf16x8*)(dst + 1*plane))[idx] = lr;
    ((bf16x8*)(dst + 2*plane))[idx] = hi;
    ((bf16x8*)(dst + 3*plane))[idx] = li;
}

// ---------------------------------------------------------------------------
// Split-bf16 complex GEMM via MFMA: C[M=2048, N] = A[2048,1024] * B[N,1024]^T
// EPI 1: fused QKV epilogue: seg = n0>>10.
//   seg 0 (Q): scale 1/8, RoPE, split -> 4 bf16 planes qp
//   seg 1 (K): RoPE, split -> 4 bf16 planes kp
//   seg 2 (V): fp32 planar store (vre, vim)
// EPI 2: interleaved (re,im) fp32 store to outI.
// ---------------------------------------------------------------------------
template<int EPI>
__global__ __launch_bounds__(256, 2)
void cgemm_mfma(const __bf16* __restrict__ A, const __bf16* __restrict__ B,
                size_t bPlane,
                __bf16* __restrict__ qp, __bf16* __restrict__ kp,
                float* __restrict__ vre, float* __restrict__ vim,
                float* __restrict__ outI)
{
    __shared__ __bf16 As[4*128*32];
    __shared__ __bf16 Bs[4*64*32];

    const int tid  = threadIdx.x;
    const int lane = tid & 63;
    const int wid  = tid >> 6;
    const int wm   = wid >> 1, wn = wid & 1;
    const int lrow = lane & 15, lk = lane >> 4;
    const int m0   = blockIdx.x * 128;
    const int n0   = blockIdx.y * 64;
    const size_t aPlane = (size_t)2048 * 1024;
    const size_t P2M = (size_t)2048 * 1024;

    f32x4 accRe[4][2], accIm[4][2];
    #pragma unroll
    for (int i = 0; i < 4; ++i)
        #pragma unroll
        for (int j = 0; j < 2; ++j) {
            accRe[i][j] = (f32x4){0.f,0.f,0.f,0.f};
            accIm[i][j] = (f32x4){0.f,0.f,0.f,0.f};
        }

    f4 prA[8], prB[4];
    #pragma unroll
    for (int i = 0; i < 8; ++i) {
        int c = tid + 256*i;
        int mat = c >> 9, row = (c >> 2) & 127, ks = c & 3;
        prA[i] = *(const f4*)(A + (size_t)mat*aPlane + (size_t)(m0+row)*1024 + ks*8);
    }
    #pragma unroll
    for (int i = 0; i < 4; ++i) {
        int c = tid + 256*i;
        int mat = c >> 8, row = (c >> 2) & 63, ks = c & 3;
        prB[i] = *(const f4*)(B + (size_t)mat*bPlane + (size_t)(n0+row)*1024 + ks*8);
    }

    const int phys = (lk ^ ((lrow >> 1) & 3)) << 3;

    for (int it = 0; it < 32; ++it) {
        __syncthreads();
        #pragma unroll
        for (int i = 0; i < 8; ++i) {
            int c = tid + 256*i;
            int mat = c >> 9, row = (c >> 2) & 127, ks = c & 3;
            int wp = (ks ^ ((row >> 1) & 3)) << 3;
            *(f4*)&As[(mat*128 + row)*32 + wp] = prA[i];
        }
        #pragma unroll
        for (int i = 0; i < 4; ++i) {
            int c = tid + 256*i;
            int mat = c >> 8, row = (c >> 2) & 63, ks = c & 3;
            int wp = (ks ^ ((row >> 1) & 3)) << 3;
            *(f4*)&Bs[(mat*64 + row)*32 + wp] = prB[i];
        }
        __syncthreads();
        if (it < 31) {
            const int k0 = (it + 1) * 32;
            #pragma unroll
            for (int i = 0; i < 8; ++i) {
                int c = tid + 256*i;
                int mat = c >> 9, row = (c >> 2) & 127, ks = c & 3;
                prA[i] = *(const f4*)(A + (size_t)mat*aPlane + (size_t)(m0+row)*1024 + k0 + ks*8);
            }
            #pragma unroll
            for (int i = 0; i < 4; ++i) {
                int c = tid + 256*i;
                int mat = c >> 8, row = (c >> 2) & 63, ks = c & 3;
                prB[i] = *(const f4*)(B + (size_t)mat*bPlane + (size_t)(n0+row)*1024 + k0 + ks*8);
            }
        }
        bf16x8 bw[2][4];
        #pragma unroll
        for (int nf = 0; nf < 2; ++nf)
            #pragma unroll
            for (int mat = 0; mat < 4; ++mat)
                bw[nf][mat] = *(const bf16x8*)&Bs[(mat*64 + wn*32 + nf*16 + lrow)*32 + phys];
        #pragma unroll
        for (int mf = 0; mf < 4; ++mf) {
            const int arow = wm*64 + mf*16 + lrow;
            bf16x8 xhr = *(const bf16x8*)&As[(0*128 + arow)*32 + phys];
            bf16x8 xlr = *(const bf16x8*)&As[(1*128 + arow)*32 + phys];
            bf16x8 xhi = *(const bf16x8*)&As[(2*128 + arow)*32 + phys];
            bf16x8 xli = *(const bf16x8*)&As[(3*128 + arow)*32 + phys];
            bf16x8 nhi = neg8(xhi), nli = neg8(xli);
            #pragma unroll
            for (int nf = 0; nf < 2; ++nf) {
                f32x4 r  = accRe[mf][nf];
                f32x4 m2 = accIm[mf][nf];
                r  = __builtin_amdgcn_mfma_f32_16x16x32_bf16(xhr, bw[nf][0], r, 0,0,0);
                r  = __builtin_amdgcn_mfma_f32_16x16x32_bf16(xhr, bw[nf][1], r, 0,0,0);
                r  = __builtin_amdgcn_mfma_f32_16x16x32_bf16(xlr, bw[nf][0], r, 0,0,0);
                r  = __builtin_amdgcn_mfma_f32_16x16x32_bf16(nhi, bw[nf][2], r, 0,0,0);
                r  = __builtin_amdgcn_mfma_f32_16x16x32_bf16(nhi, bw[nf][3], r, 0,0,0);
                r  = __builtin_amdgcn_mfma_f32_16x16x32_bf16(nli, bw[nf][2], r, 0,0,0);
                m2 = __builtin_amdgcn_mfma_f32_16x16x32_bf16(xhr, bw[nf][2], m2, 0,0,0);
                m2 = __builtin_amdgcn_mfma_f32_16x16x32_bf16(xhr, bw[nf][3], m2, 0,0,0);
                m2 = __builtin_amdgcn_mfma_f32_16x16x32_bf16(xlr, bw[nf][2], m2, 0,0,0);
                m2 = __builtin_amdgcn_mfma_f32_16x16x32_bf16(xhi, bw[nf][0], m2, 0,0,0);
                m2 = __builtin_amdgcn_mfma_f32_16x16x32_bf16(xhi, bw[nf][1], m2, 0,0,0);
                m2 = __builtin_amdgcn_mfma_f32_16x16x32_bf16(xli, bw[nf][0], m2, 0,0,0);
                accRe[mf][nf] = r; accIm[mf][nf] = m2;
            }
        }
    }

    const int seg  = n0 >> 10;
    const int nloc = n0 & 1023;
    #pragma unroll
    for (int mf = 0; mf < 4; ++mf) {
        #pragma unroll
        for (int nf = 0; nf < 2; ++nf) {
            const int colB = wn*32 + nf*16 + lrow;   // 0..63 == dh
            f32x4 r  = accRe[mf][nf];
            f32x4 m2 = accIm[mf][nf];
            float invf = 0.f;
            if (EPI == 1 && seg < 2) invf = __expf(-(float)colB * 0.14391157f); // ln(1e4)/64
            #pragma unroll
            for (int rg = 0; rg < 4; ++rg) {
                const int m = m0 + wm*64 + mf*16 + lk*4 + rg;
                float re = r[rg], im = m2[rg];
                if (EPI == 1) {
                    if (seg == 0) { re *= 0.125f; im *= 0.125f; }  // fold 1/sqrt(Dh) into Q
                    if (seg < 2) {
                        float sn, cs;
                        __sincosf((float)(m & (S_LEN-1)) * invf, &sn, &cs);
                        float t = re*cs - im*sn;
                        im = re*sn + im*cs; re = t;
                        // split to 4 bf16 planes
                        __bf16 h1 = (__bf16)re; __bf16 l1 = (__bf16)(re - (float)h1);
                        __bf16 h2 = (__bf16)im; __bf16 l2 = (__bf16)(im - (float)h2);
                        __bf16* dp = (seg == 0) ? qp : kp;
                        size_t off = (size_t)m*1024 + nloc + colB;
                        dp[off] = h1; dp[P2M + off] = l1;
                        dp[2*P2M + off] = h2; dp[3*P2M + off] = l2;
                    } else {
                        size_t off = (size_t)m*1024 + nloc + colB;
                        vre[off] = re; vim[off] = im;
                    }
                } else {
                    size_t off = ((size_t)m*1024 + nloc + colB)*2;
                    outI[off] = re; outI[off+1] = im;
                }
            }
        }
    }
}

// ---------------------------------------------------------------------------
// V transpose prep: fp32 planar V[2048][1024] -> bf16 Vt[2][32bh][64 d][1024 s]
// ---------------------------------------------------------------------------
__global__ __launch_bounds__(256)
void transpose_v(const float* __restrict__ Vre, const float* __restrict__ Vim,
                 __bf16* __restrict__ Vt)
{
    __shared__ float T[2][64][65];
    const int tid = threadIdx.x;
    const int s0  = blockIdx.x * 64;
    const int bh  = blockIdx.y;
    const int b   = bh >> 4, h = bh & 15;
    const size_t P2M = (size_t)2048 * 1024;

    #pragma unroll
    for (int r = 0; r < 4; ++r) {
        int c   = tid + 256*r;          // 0..1023
        int row = c >> 4, cc = c & 15;  // 16 float4 per row
        size_t off = (size_t)(b*1024 + s0 + row)*1024 + h*64 + cc*4;
        float4 vr = *(const float4*)(Vre + off);
        float4 vi = *(const float4*)(Vim + off);
        T[0][row][cc*4+0] = vr.x; T[0][row][cc*4+1] = vr.y;
        T[0][row][cc*4+2] = vr.z; T[0][row][cc*4+3] = vr.w;
        T[1][row][cc*4+0] = vi.x; T[1][row][cc*4+1] = vi.y;
        T[1][row][cc*4+2] = vi.z; T[1][row][cc*4+3] = vi.w;
    }
    __syncthreads();
    #pragma unroll
    for (int r = 0; r < 4; ++r) {
        int c  = tid + 256*r;           // 0..1023
        int p  = c >> 9, d = (c >> 3) & 63, sc = c & 7;
        bf16x8 o;
        #pragma unroll
        for (int j = 0; j < 8; ++j) o[j] = (__bf16)T[p][sc*8+j][d];
        *(bf16x8*)(Vt + (size_t)p*P2M + (size_t)(bh*64 + d)*1024 + s0 + sc*8) = o;
    }
}

// ---------------------------------------------------------------------------
// MFMA flash attention.
// grid (S/64, 32 bh), 256 threads = 4 waves; wave w owns queries w*16..+15.
// KVBLK=32. QK^H split-bf16 (12 MFMA/frag-pair); PV plain bf16.
// Q frags loaded from global split planes into registers (persistent).
// ---------------------------------------------------------------------------
__global__ __launch_bounds__(256)
void flash_mfma(const __bf16* __restrict__ Qp, const __bf16* __restrict__ Kp,
                const __bf16* __restrict__ Vt,
                float* __restrict__ Ore, float* __restrict__ Oim)
{
    __shared__ __align__(16) __bf16 Ks[4][32][72];   // [plane][key][dh] pad
    __shared__ __align__(16) __bf16 Vs[2][64][40];   // [plane][d][key] pad
    __shared__ __align__(16) __bf16 Pa[4][16][40];   // per-wave P real
    __shared__ __align__(16) __bf16 Pb[4][16][40];   // per-wave P imag

    const int tid  = threadIdx.x;
    const int lane = tid & 63;
    const int w    = tid >> 6;
    const int lq   = lane & 15;
    const int g    = lane >> 4;       // 0..3
    const int q0   = blockIdx.x * 64;
    const int bh   = blockIdx.y;
    const int b    = bh >> 4, h = bh & 15;
    const size_t P2M = (size_t)2048 * 1024;

    // ---- persistent Q fragments: qf[plane][kchunk] ----
    bf16x8 qf[4][2];
    {
        const size_t qrow = (size_t)(b*1024 + q0 + w*16 + lq) * 1024 + h*64;
        #pragma unroll
        for (int p = 0; p < 4; ++p)
            #pragma unroll
            for (int kc = 0; kc < 2; ++kc)
                qf[p][kc] = *(const bf16x8*)(Qp + (size_t)p*P2M + qrow + kc*32 + g*8);
    }

    f32x4 oRe[4], oIm[4];
    #pragma unroll
    for (int d = 0; d < 4; ++d) { oRe[d] = (f32x4){0,0,0,0}; oIm[d] = (f32x4){0,0,0,0}; }
    float mrow[4], lsum[4];
    #pragma unroll
    for (int i = 0; i < 4; ++i) { mrow[i] = -INFINITY; lsum[i] = 0.f; }

    // ---- prefetch K/V tile 0 ----
    bf16x8 pk[4]; bf16x8 pv[2];
    #pragma unroll
    for (int i = 0; i < 4; ++i) {
        int c = tid + 256*i;            // 0..1023
        int p = c >> 8, key = (c >> 3) & 31, cc = c & 7;
        pk[i] = *(const bf16x8*)(Kp + (size_t)p*P2M + (size_t)(b*1024 + key)*1024 + h*64 + cc*8);
    }
    #pragma unroll
    for (int i = 0; i < 2; ++i) {
        int c = tid + 256*i;            // 0..511
        int p = c >> 8, d = (c >> 2) & 63, cc = c & 3;
        pv[i] = *(const bf16x8*)(Vt + (size_t)p*P2M + (size_t)(bh*64 + d)*1024 + cc*8);
    }

    for (int it = 0; it < 32; ++it) {
        __syncthreads();
        // ---- write staged K/V from regs ----
        #pragma unroll
        for (int i = 0; i < 4; ++i) {
            int c = tid + 256*i;
            int p = c >> 8, key = (c >> 3) & 31, cc = c & 7;
            *(bf16x8*)&Ks[p][key][cc*8] = pk[i];
        }
        #pragma unroll
        for (int i = 0; i < 2; ++i) {
            int c = tid + 256*i;
            int p = c >> 8, d = (c >> 2) & 63, cc = c & 3;
            *(bf16x8*)&Vs[p][d][cc*8] = pv[i];
        }
        // ---- issue next-tile prefetch ----
        if (it < 31) {
            const int t0 = (it + 1) * 32;
            #pragma unroll
            for (int i = 0; i < 4; ++i) {
                int c = tid + 256*i;
                int p = c >> 8, key = (c >> 3) & 31, cc = c & 7;
                pk[i] = *(const bf16x8*)(Kp + (size_t)p*P2M + (size_t)(b*1024 + t0 + key)*1024 + h*64 + cc*8);
            }
            #pragma unroll
            for (int i = 0; i < 2; ++i) {
                int c = tid + 256*i;
                int p = c >> 8, d = (c >> 2) & 63, cc = c & 3;
                pv[i] = *(const bf16x8*)(Vt + (size_t)p*P2M + (size_t)(bh*64 + d)*1024 + t0 + cc*8);
            }
        }
        __syncthreads();

        // ---- QK^H: S[16q][32k] split-bf16, fp32 accum ----
        f32x4 sRe[2], sIm[2];
        #pragma unroll
        for (int f = 0; f < 2; ++f) { sRe[f] = (f32x4){0,0,0,0}; sIm[f] = (f32x4){0,0,0,0}; }
        #pragma unroll
        for (int kc = 0; kc < 2; ++kc) {
            #pragma unroll
            for (int f = 0; f < 2; ++f) {
                const int key = f*16 + lq;
                bf16x8 krh = *(const bf16x8*)&Ks[0][key][kc*32 + g*8];
                bf16x8 krl = *(const bf16x8*)&Ks[1][key][kc*32 + g*8];
                bf16x8 kih = *(const bf16x8*)&Ks[2][key][kc*32 + g*8];
                bf16x8 kil = *(const bf16x8*)&Ks[3][key][kc*32 + g*8];
                bf16x8 nkih = neg8(kih), nkil = neg8(kil);
                f32x4 r = sRe[f], m2 = sIm[f];
                // Re = qr*kr + qi*ki  (3-pass split each)
                r  = __builtin_amdgcn_mfma_f32_16x16x32_bf16(qf[0][kc], krh, r, 0,0,0);
                r  = __builtin_amdgcn_mfma_f32_16x16x32_bf16(qf[0][kc], krl, r, 0,0,0);
                r  = __builtin_amdgcn_mfma_f32_16x16x32_bf16(qf[1][kc], krh, r, 0,0,0);
                r  = __builtin_amdgcn_mfma_f32_16x16x32_bf16(qf[2][kc], kih, r, 0,0,0);
                r  = __builtin_amdgcn_mfma_f32_16x16x32_bf16(qf[2][kc], kil, r, 0,0,0);
                r  = __builtin_amdgcn_mfma_f32_16x16x32_bf16(qf[3][kc], kih, r, 0,0,0);
                // Im = qi*kr - qr*ki
                m2 = __builtin_amdgcn_mfma_f32_16x16x32_bf16(qf[2][kc], krh, m2, 0,0,0);
                m2 = __builtin_amdgcn_mfma_f32_16x16x32_bf16(qf[2][kc], krl, m2, 0,0,0);
                m2 = __builtin_amdgcn_mfma_f32_16x16x32_bf16(qf[3][kc], krh, m2, 0,0,0);
                m2 = __builtin_amdgcn_mfma_f32_16x16x32_bf16(qf[0][kc], nkih, m2, 0,0,0);
                m2 = __builtin_amdgcn_mfma_f32_16x16x32_bf16(qf[0][kc], nkil, m2, 0,0,0);
                m2 = __builtin_amdgcn_mfma_f32_16x16x32_bf16(qf[1][kc], nkih, m2, 0,0,0);
                sRe[f] = r; sIm[f] = m2;
            }
        }

        // ---- online softmax + rotor; pack P to LDS bf16 ----
        float esc[4];
        #pragma unroll
        for (int i = 0; i < 4; ++i) {
            float s0 = sRe[0][i], s1 = sRe[1][i];
            float tmax = fmaxf(s0, s1);
            #pragma unroll
            for (int mm = 1; mm < 16; mm <<= 1) tmax = fmaxf(tmax, __shfl_xor(tmax, mm, 16));
            float mnew = fmaxf(mrow[i], tmax);
            float p0 = __expf(s0 - mnew);
            float p1 = __expf(s1 - mnew);
            float ps = p0 + p1;
            #pragma unroll
            for (int mm = 1; mm < 16; mm <<= 1) ps += __shfl_xor(ps, mm, 16);
            esc[i]  = __expf(mrow[i] - mnew);
            lsum[i] = lsum[i]*esc[i] + ps;
            mrow[i] = mnew;
            float sn0, cs0, sn1, cs1;
            __sincosf(sIm[0][i], &sn0, &cs0);
            __sincosf(sIm[1][i], &sn1, &cs1);
            const int row = g*4 + i;
            Pa[w][row][lq]      = (__bf16)(p0*cs0);
            Pa[w][row][16 + lq] = (__bf16)(p1*cs1);
            Pb[w][row][lq]      = (__bf16)(p0*sn0);
            Pb[w][row][16 + lq] = (__bf16)(p1*sn1);
        }
        #pragma unroll
        for (int d = 0; d < 4; ++d)
            #pragma unroll
            for (int i = 0; i < 4; ++i) { oRe[d][i] *= esc[i]; oIm[d][i] *= esc[i]; }

        // ---- PV: O[16q][64d] += P * V  (plain bf16) ----
        bf16x8 pa  = *(const bf16x8*)&Pa[w][lq][g*8];
        bf16x8 pb  = *(const bf16x8*)&Pb[w][lq][g*8];
        bf16x8 npb = neg8(pb);
        #pragma unroll
        for (int df = 0; df < 4; ++df) {
            bf16x8 vr = *(const bf16x8*)&Vs[0][df*16 + lq][g*8];
            bf16x8 vi = *(const bf16x8*)&Vs[1][df*16 + lq][g*8];
            oRe[df] = __builtin_amdgcn_mfma_f32_16x16x32_bf16(pa,  vr, oRe[df], 0,0,0);
            oRe[df] = __builtin_amdgcn_mfma_f32_16x16x32_bf16(npb, vi, oRe[df], 0,0,0);
            oIm[df] = __builtin_amdgcn_mfma_f32_16x16x32_bf16(pa,  vi, oIm[df], 0,0,0);
            oIm[df] = __builtin_amdgcn_mfma_f32_16x16x32_bf16(pb,  vr, oIm[df], 0,0,0);
        }
    }

    // ---- normalize + store fp32 planar ----
    #pragma unroll
    for (int i = 0; i < 4; ++i) {
        const float inv = 1.f / lsum[i];
        const size_t rowOff = (size_t)(b*1024 + q0 + w*16 + g*4 + i) * 1024 + h*64;
        #pragma unroll
        for (int df = 0; df < 4; ++df) {
            Ore[rowOff + df*16 + lq] = oRe[df][i] * inv;
            Oim[rowOff + df*16 + lq] = oIm[df][i] * inv;
        }
    }
}

// ---------------------------------------------------------------------------
extern "C" void kernel_launch(void* const* d_in, const int* in_sizes, int n_in,
                              void* d_out, int out_size, void* d_ws, size_t ws_size,
                              hipStream_t stream)
{
    (void)in_sizes; (void)n_in; (void)out_size; (void)ws_size;
    const float* x_re  = (const float*)d_in[0];
    const float* x_im  = (const float*)d_in[1];
    const float* wq_re = (const float*)d_in[2];
    const float* wq_im = (const float*)d_in[3];
    const float* wk_re = (const float*)d_in[4];
    const float* wk_im = (const float*)d_in[5];
    const float* wv_re = (const float*)d_in[6];
    const float* wv_im = (const float*)d_in[7];
    const float* wo_re = (const float*)d_in[8];
    const float* wo_im = (const float*)d_in[9];
    float* out = (float*)d_out;

    char* wsb = (char*)d_ws;
    const size_t MB = (size_t)1 << 20;
    // [0,16)   x_s (bf16 4 planes)  -> later O fp32 (re@0, im@8MB)
    // [16,40)  wqkv_s (bf16 4x3M)   -> later Vt (bf16 2 planes) @16
    // [40,48)  wo_s
    // [48,64)  Q planes (bf16 4x2M)
    // [64,80)  K planes (bf16 4x2M) -> later o_s (bf16 4x2M)
    // [80,96)  V fp32 (re@80, im@88)
    __bf16* x_s    = (__bf16*)(wsb +  0*MB);
    float*  Ore    = (float*) (wsb +  0*MB);
    float*  Oim    = (float*) (wsb +  8*MB);
    __bf16* wqkv_s = (__bf16*)(wsb + 16*MB);
    __bf16* Vt_g   = (__bf16*)(wsb + 16*MB);
    __bf16* wo_s   = (__bf16*)(wsb + 40*MB);
    __bf16* Qs_g   = (__bf16*)(wsb + 48*MB);
    __bf16* Ks_g   = (__bf16*)(wsb + 64*MB);
    __bf16* o_s    = (__bf16*)(wsb + 64*MB);
    float*  Vre    = (float*) (wsb + 80*MB);
    float*  Vim    = (float*) (wsb + 88*MB);

    const size_t P1M = (size_t)1024 * 1024;
    const size_t P2M = 2 * P1M;
    const size_t P3M = 3 * P1M;

    split_bf16<<<1024, 256, 0, stream>>>(x_re, x_im, x_s, P2M, (int)(P2M/8));
    split_bf16<<< 512, 256, 0, stream>>>(wq_re, wq_im, wqkv_s,         P3M, (int)(P1M/8));
    split_bf16<<< 512, 256, 0, stream>>>(wk_re, wk_im, wqkv_s + P1M,   P3M, (int)(P1M/8));
    split_bf16<<< 512, 256, 0, stream>>>(wv_re, wv_im, wqkv_s + 2*P1M, P3M, (int)(P1M/8));
    split_bf16<<< 512, 256, 0, stream>>>(wo_re, wo_im, wo_s, P1M, (int)(P1M/8));

    // fused QKV projection: Q/K -> RoPE'd split-bf16 planes, V -> fp32
    cgemm_mfma<1><<<dim3(16, 48), 256, 0, stream>>>(x_s, wqkv_s, P3M,
                                                    Qs_g, Ks_g, Vre, Vim, nullptr);
    // V transpose to per-head [d][s] bf16
    transpose_v<<<dim3(16, 32), 256, 0, stream>>>(Vre, Vim, Vt_g);
    // MFMA flash attention -> O fp32 (overwrites dead x_s region)
    flash_mfma<<<dim3(16, 32), 256, 0, stream>>>(Qs_g, Ks_g, Vt_g, Ore, Oim);
    // split O and project
    split_bf16<<<1024, 256, 0, stream>>>(Ore, Oim, o_s, P2M, (int)(P2M/8));
    cgemm_mfma<2><<<dim3(16, 16), 256, 0, stream>>>(o_s, wo_s, P1M,
                                                    nullptr, nullptr, nullptr, nullptr, out);
}

// Round 5
// 311.611 us; speedup vs baseline: 4.4223x; 1.0675x over previous
//
#include <hip/hip_runtime.h>
#include <math.h>

#define S_LEN  1024
#define DMODEL 1024
#define DH     64

typedef float  f4     __attribute__((ext_vector_type(4)));
typedef float  f32x4  __attribute__((ext_vector_type(4)));
typedef __bf16 bf16x8 __attribute__((ext_vector_type(8)));
typedef unsigned int u32x4 __attribute__((ext_vector_type(4)));

__device__ __forceinline__ bf16x8 neg8(bf16x8 v) {
    u32x4 u;
    __builtin_memcpy(&u, &v, 16);
    u ^= 0x80008000u;
    bf16x8 r;
    __builtin_memcpy(&r, &u, 16);
    return r;
}

// ---------------------------------------------------------------------------
// Split fp32 (re,im) into bf16 hi/lo planes: dst + {0,1,2,3}*plane = hr,lr,hi,li
// ---------------------------------------------------------------------------
__global__ __launch_bounds__(256)
void split_bf16(const float* __restrict__ re, const float* __restrict__ im,
                __bf16* __restrict__ dst, size_t plane, int n8)
{
    int idx = blockIdx.x * 256 + threadIdx.x;
    if (idx >= n8) return;
    f4 r0 = ((const f4*)re)[idx*2];
    f4 r1 = ((const f4*)re)[idx*2+1];
    f4 i0 = ((const f4*)im)[idx*2];
    f4 i1 = ((const f4*)im)[idx*2+1];
    float rr[8] = {r0.x,r0.y,r0.z,r0.w,r1.x,r1.y,r1.z,r1.w};
    float ii[8] = {i0.x,i0.y,i0.z,i0.w,i1.x,i1.y,i1.z,i1.w};
    bf16x8 hr, lr, hi, li;
    #pragma unroll
    for (int j = 0; j < 8; ++j) {
        __bf16 h = (__bf16)rr[j];
        hr[j] = h; lr[j] = (__bf16)(rr[j] - (float)h);
        __bf16 g = (__bf16)ii[j];
        hi[j] = g; li[j] = (__bf16)(ii[j] - (float)g);
    }
    ((bf16x8*)(dst + 0*plane))[idx] = hr;
    ((bf16x8*)(dst + 1*plane))[idx] = lr;
    ((bf16x8*)(dst + 2*plane))[idx] = hi;
    ((bf16x8*)(dst + 3*plane))[idx] = li;
}

// ---------------------------------------------------------------------------
// Split-bf16 complex GEMM via MFMA: C[M=2048, N] = A[2048,1024] * B[N,1024]^T
// EPI 1 (QKV): seg = n0>>10.
//   seg 0 (Q): scale 1/8, RoPE, split -> 4 bf16 planes qp
//   seg 1 (K): RoPE, split -> 4 bf16 planes kp
//   seg 2 (V): direct bf16 planar store (2 planes in vb)
// EPI 2: interleaved (re,im) fp32 store to outI.
// ---------------------------------------------------------------------------
template<int EPI>
__global__ __launch_bounds__(256, 2)
void cgemm_mfma(const __bf16* __restrict__ A, const __bf16* __restrict__ B,
                size_t bPlane,
                __bf16* __restrict__ qp, __bf16* __restrict__ kp,
                __bf16* __restrict__ vb, float* __restrict__ outI)
{
    __shared__ __bf16 As[4*128*32];
    __shared__ __bf16 Bs[4*64*32];

    const int tid  = threadIdx.x;
    const int lane = tid & 63;
    const int wid  = tid >> 6;
    const int wm   = wid >> 1, wn = wid & 1;
    const int lrow = lane & 15, lk = lane >> 4;
    const int m0   = blockIdx.x * 128;
    const int n0   = blockIdx.y * 64;
    const size_t aPlane = (size_t)2048 * 1024;
    const size_t P2M = (size_t)2048 * 1024;

    f32x4 accRe[4][2], accIm[4][2];
    #pragma unroll
    for (int i = 0; i < 4; ++i)
        #pragma unroll
        for (int j = 0; j < 2; ++j) {
            accRe[i][j] = (f32x4){0.f,0.f,0.f,0.f};
            accIm[i][j] = (f32x4){0.f,0.f,0.f,0.f};
        }

    f4 prA[8], prB[4];
    #pragma unroll
    for (int i = 0; i < 8; ++i) {
        int c = tid + 256*i;
        int mat = c >> 9, row = (c >> 2) & 127, ks = c & 3;
        prA[i] = *(const f4*)(A + (size_t)mat*aPlane + (size_t)(m0+row)*1024 + ks*8);
    }
    #pragma unroll
    for (int i = 0; i < 4; ++i) {
        int c = tid + 256*i;
        int mat = c >> 8, row = (c >> 2) & 63, ks = c & 3;
        prB[i] = *(const f4*)(B + (size_t)mat*bPlane + (size_t)(n0+row)*1024 + ks*8);
    }

    const int phys = (lk ^ ((lrow >> 1) & 3)) << 3;

    for (int it = 0; it < 32; ++it) {
        __syncthreads();
        #pragma unroll
        for (int i = 0; i < 8; ++i) {
            int c = tid + 256*i;
            int mat = c >> 9, row = (c >> 2) & 127, ks = c & 3;
            int wp = (ks ^ ((row >> 1) & 3)) << 3;
            *(f4*)&As[(mat*128 + row)*32 + wp] = prA[i];
        }
        #pragma unroll
        for (int i = 0; i < 4; ++i) {
            int c = tid + 256*i;
            int mat = c >> 8, row = (c >> 2) & 63, ks = c & 3;
            int wp = (ks ^ ((row >> 1) & 3)) << 3;
            *(f4*)&Bs[(mat*64 + row)*32 + wp] = prB[i];
        }
        __syncthreads();
        if (it < 31) {
            const int k0 = (it + 1) * 32;
            #pragma unroll
            for (int i = 0; i < 8; ++i) {
                int c = tid + 256*i;
                int mat = c >> 9, row = (c >> 2) & 127, ks = c & 3;
                prA[i] = *(const f4*)(A + (size_t)mat*aPlane + (size_t)(m0+row)*1024 + k0 + ks*8);
            }
            #pragma unroll
            for (int i = 0; i < 4; ++i) {
                int c = tid + 256*i;
                int mat = c >> 8, row = (c >> 2) & 63, ks = c & 3;
                prB[i] = *(const f4*)(B + (size_t)mat*bPlane + (size_t)(n0+row)*1024 + k0 + ks*8);
            }
        }
        bf16x8 bw[2][4];
        #pragma unroll
        for (int nf = 0; nf < 2; ++nf)
            #pragma unroll
            for (int mat = 0; mat < 4; ++mat)
                bw[nf][mat] = *(const bf16x8*)&Bs[(mat*64 + wn*32 + nf*16 + lrow)*32 + phys];
        __builtin_amdgcn_s_setprio(1);
        #pragma unroll
        for (int mf = 0; mf < 4; ++mf) {
            const int arow = wm*64 + mf*16 + lrow;
            bf16x8 xhr = *(const bf16x8*)&As[(0*128 + arow)*32 + phys];
            bf16x8 xlr = *(const bf16x8*)&As[(1*128 + arow)*32 + phys];
            bf16x8 xhi = *(const bf16x8*)&As[(2*128 + arow)*32 + phys];
            bf16x8 xli = *(const bf16x8*)&As[(3*128 + arow)*32 + phys];
            bf16x8 nhi = neg8(xhi), nli = neg8(xli);
            #pragma unroll
            for (int nf = 0; nf < 2; ++nf) {
                f32x4 r  = accRe[mf][nf];
                f32x4 m2 = accIm[mf][nf];
                r  = __builtin_amdgcn_mfma_f32_16x16x32_bf16(xhr, bw[nf][0], r, 0,0,0);
                r  = __builtin_amdgcn_mfma_f32_16x16x32_bf16(xhr, bw[nf][1], r, 0,0,0);
                r  = __builtin_amdgcn_mfma_f32_16x16x32_bf16(xlr, bw[nf][0], r, 0,0,0);
                r  = __builtin_amdgcn_mfma_f32_16x16x32_bf16(nhi, bw[nf][2], r, 0,0,0);
                r  = __builtin_amdgcn_mfma_f32_16x16x32_bf16(nhi, bw[nf][3], r, 0,0,0);
                r  = __builtin_amdgcn_mfma_f32_16x16x32_bf16(nli, bw[nf][2], r, 0,0,0);
                m2 = __builtin_amdgcn_mfma_f32_16x16x32_bf16(xhr, bw[nf][2], m2, 0,0,0);
                m2 = __builtin_amdgcn_mfma_f32_16x16x32_bf16(xhr, bw[nf][3], m2, 0,0,0);
                m2 = __builtin_amdgcn_mfma_f32_16x16x32_bf16(xlr, bw[nf][2], m2, 0,0,0);
                m2 = __builtin_amdgcn_mfma_f32_16x16x32_bf16(xhi, bw[nf][0], m2, 0,0,0);
                m2 = __builtin_amdgcn_mfma_f32_16x16x32_bf16(xhi, bw[nf][1], m2, 0,0,0);
                m2 = __builtin_amdgcn_mfma_f32_16x16x32_bf16(xli, bw[nf][0], m2, 0,0,0);
                accRe[mf][nf] = r; accIm[mf][nf] = m2;
            }
        }
        __builtin_amdgcn_s_setprio(0);
    }

    const int seg  = n0 >> 10;
    const int nloc = n0 & 1023;
    #pragma unroll
    for (int mf = 0; mf < 4; ++mf) {
        #pragma unroll
        for (int nf = 0; nf < 2; ++nf) {
            const int colB = wn*32 + nf*16 + lrow;   // 0..63 == dh
            f32x4 r  = accRe[mf][nf];
            f32x4 m2 = accIm[mf][nf];
            float invf = 0.f;
            if (EPI == 1 && seg < 2) invf = __expf(-(float)colB * 0.14391157f); // ln(1e4)/64
            #pragma unroll
            for (int rg = 0; rg < 4; ++rg) {
                const int m = m0 + wm*64 + mf*16 + lk*4 + rg;
                float re = r[rg], im = m2[rg];
                if (EPI == 1) {
                    if (seg == 0) { re *= 0.125f; im *= 0.125f; }  // fold 1/sqrt(Dh) into Q
                    if (seg < 2) {
                        float sn, cs;
                        __sincosf((float)(m & (S_LEN-1)) * invf, &sn, &cs);
                        float t = re*cs - im*sn;
                        im = re*sn + im*cs; re = t;
                        __bf16 h1 = (__bf16)re; __bf16 l1 = (__bf16)(re - (float)h1);
                        __bf16 h2 = (__bf16)im; __bf16 l2 = (__bf16)(im - (float)h2);
                        __bf16* dp = (seg == 0) ? qp : kp;
                        size_t off = (size_t)m*1024 + nloc + colB;
                        dp[off] = h1; dp[P2M + off] = l1;
                        dp[2*P2M + off] = h2; dp[3*P2M + off] = l2;
                    } else {
                        size_t off = (size_t)m*1024 + nloc + colB;
                        vb[off] = (__bf16)re; vb[P2M + off] = (__bf16)im;
                    }
                } else {
                    size_t off = ((size_t)m*1024 + nloc + colB)*2;
                    outI[off] = re; outI[off+1] = im;
                }
            }
        }
    }
}

// ---------------------------------------------------------------------------
// V transpose prep: bf16 planar V[2][2048][1024] -> bf16 Vt[2][32bh][64 d][1024 s]
// ---------------------------------------------------------------------------
__global__ __launch_bounds__(256)
void transpose_v(const __bf16* __restrict__ Vb, __bf16* __restrict__ Vt)
{
    __shared__ __bf16 T[2][64][72];
    const int tid = threadIdx.x;
    const int s0  = blockIdx.x * 64;
    const int bh  = blockIdx.y;
    const int b   = bh >> 4, h = bh & 15;
    const size_t P2M = (size_t)2048 * 1024;

    #pragma unroll
    for (int i = 0; i < 4; ++i) {
        int c = tid + 256*i;            // 0..1023
        int p = c >> 9, row = (c >> 3) & 63, cc = c & 7;
        bf16x8 v = *(const bf16x8*)(Vb + (size_t)p*P2M + (size_t)(b*1024 + s0 + row)*1024 + h*64 + cc*8);
        *(bf16x8*)&T[p][row][cc*8] = v;
    }
    __syncthreads();
    #pragma unroll
    for (int i = 0; i < 4; ++i) {
        int c = tid + 256*i;
        int p = c >> 9, d = (c >> 3) & 63, sc = c & 7;
        bf16x8 o;
        #pragma unroll
        for (int j = 0; j < 8; ++j) o[j] = T[p][sc*8+j][d];
        *(bf16x8*)(Vt + (size_t)p*P2M + (size_t)(bh*64 + d)*1024 + s0 + sc*8) = o;
    }
}

// ---------------------------------------------------------------------------
// MFMA flash attention v3.
// grid (S/32, 32 bh), 128 threads = 2 waves; wave w owns queries q0+w*16..+15.
// KVBLK=32, 1024 blocks (4/CU). QK^H split-bf16, PV plain bf16.
// T13 defer-max (THR=8), T5 setprio around MFMA clusters.
// Epilogue stores O directly as 4 split-bf16 planes (feeds O-projection).
// ---------------------------------------------------------------------------
__global__ __launch_bounds__(128, 2)
void flash_mfma(const __bf16* __restrict__ Qp, const __bf16* __restrict__ Kp,
                const __bf16* __restrict__ Vt, __bf16* __restrict__ Os)
{
    __shared__ __align__(16) __bf16 Ks[4][32][72];   // [plane][key][dh] pad
    __shared__ __align__(16) __bf16 Vs[2][64][40];   // [plane][d][key] pad
    __shared__ __align__(16) __bf16 Pa[2][16][40];   // per-wave P real
    __shared__ __align__(16) __bf16 Pb[2][16][40];   // per-wave P imag

    const int tid  = threadIdx.x;
    const int lane = tid & 63;
    const int w    = tid >> 6;
    const int lq   = lane & 15;
    const int g    = lane >> 4;       // 0..3
    const int q0   = blockIdx.x * 32;
    const int bh   = blockIdx.y;
    const int b    = bh >> 4, h = bh & 15;
    const size_t P2M = (size_t)2048 * 1024;

    // ---- persistent Q fragments: qf[plane][kchunk] ----
    bf16x8 qf[4][2];
    {
        const size_t qrow = (size_t)(b*1024 + q0 + w*16 + lq) * 1024 + h*64;
        #pragma unroll
        for (int p = 0; p < 4; ++p)
            #pragma unroll
            for (int kc = 0; kc < 2; ++kc)
                qf[p][kc] = *(const bf16x8*)(Qp + (size_t)p*P2M + qrow + kc*32 + g*8);
    }

    f32x4 oRe[4], oIm[4];
    #pragma unroll
    for (int d = 0; d < 4; ++d) { oRe[d] = (f32x4){0,0,0,0}; oIm[d] = (f32x4){0,0,0,0}; }
    float mrow[4], lsum[4];
    #pragma unroll
    for (int i = 0; i < 4; ++i) { mrow[i] = -INFINITY; lsum[i] = 0.f; }

    // ---- prefetch K/V tile 0 ----
    bf16x8 pk[8]; bf16x8 pv[4];
    #pragma unroll
    for (int i = 0; i < 8; ++i) {
        int c = tid + 128*i;            // 0..1023
        int p = c >> 8, key = (c >> 3) & 31, cc = c & 7;
        pk[i] = *(const bf16x8*)(Kp + (size_t)p*P2M + (size_t)(b*1024 + key)*1024 + h*64 + cc*8);
    }
    #pragma unroll
    for (int i = 0; i < 4; ++i) {
        int c = tid + 128*i;            // 0..511
        int p = c >> 8, d = (c >> 2) & 63, cc = c & 3;
        pv[i] = *(const bf16x8*)(Vt + (size_t)p*P2M + (size_t)(bh*64 + d)*1024 + cc*8);
    }

    for (int it = 0; it < 32; ++it) {
        __syncthreads();
        // ---- write staged K/V from regs ----
        #pragma unroll
        for (int i = 0; i < 8; ++i) {
            int c = tid + 128*i;
            int p = c >> 8, key = (c >> 3) & 31, cc = c & 7;
            *(bf16x8*)&Ks[p][key][cc*8] = pk[i];
        }
        #pragma unroll
        for (int i = 0; i < 4; ++i) {
            int c = tid + 128*i;
            int p = c >> 8, d = (c >> 2) & 63, cc = c & 3;
            *(bf16x8*)&Vs[p][d][cc*8] = pv[i];
        }
        // ---- issue next-tile prefetch ----
        if (it < 31) {
            const int t0 = (it + 1) * 32;
            #pragma unroll
            for (int i = 0; i < 8; ++i) {
                int c = tid + 128*i;
                int p = c >> 8, key = (c >> 3) & 31, cc = c & 7;
                pk[i] = *(const bf16x8*)(Kp + (size_t)p*P2M + (size_t)(b*1024 + t0 + key)*1024 + h*64 + cc*8);
            }
            #pragma unroll
            for (int i = 0; i < 4; ++i) {
                int c = tid + 128*i;
                int p = c >> 8, d = (c >> 2) & 63, cc = c & 3;
                pv[i] = *(const bf16x8*)(Vt + (size_t)p*P2M + (size_t)(bh*64 + d)*1024 + t0 + cc*8);
            }
        }
        __syncthreads();

        // ---- QK^H: S[16q][32k] split-bf16, fp32 accum ----
        f32x4 sRe[2], sIm[2];
        #pragma unroll
        for (int f = 0; f < 2; ++f) { sRe[f] = (f32x4){0,0,0,0}; sIm[f] = (f32x4){0,0,0,0}; }
        __builtin_amdgcn_s_setprio(1);
        #pragma unroll
        for (int kc = 0; kc < 2; ++kc) {
            #pragma unroll
            for (int f = 0; f < 2; ++f) {
                const int key = f*16 + lq;
                bf16x8 krh = *(const bf16x8*)&Ks[0][key][kc*32 + g*8];
                bf16x8 krl = *(const bf16x8*)&Ks[1][key][kc*32 + g*8];
                bf16x8 kih = *(const bf16x8*)&Ks[2][key][kc*32 + g*8];
                bf16x8 kil = *(const bf16x8*)&Ks[3][key][kc*32 + g*8];
                bf16x8 nkih = neg8(kih), nkil = neg8(kil);
                f32x4 r = sRe[f], m2 = sIm[f];
                r  = __builtin_amdgcn_mfma_f32_16x16x32_bf16(qf[0][kc], krh, r, 0,0,0);
                r  = __builtin_amdgcn_mfma_f32_16x16x32_bf16(qf[0][kc], krl, r, 0,0,0);
                r  = __builtin_amdgcn_mfma_f32_16x16x32_bf16(qf[1][kc], krh, r, 0,0,0);
                r  = __builtin_amdgcn_mfma_f32_16x16x32_bf16(qf[2][kc], kih, r, 0,0,0);
                r  = __builtin_amdgcn_mfma_f32_16x16x32_bf16(qf[2][kc], kil, r, 0,0,0);
                r  = __builtin_amdgcn_mfma_f32_16x16x32_bf16(qf[3][kc], kih, r, 0,0,0);
                m2 = __builtin_amdgcn_mfma_f32_16x16x32_bf16(qf[2][kc], krh, m2, 0,0,0);
                m2 = __builtin_amdgcn_mfma_f32_16x16x32_bf16(qf[2][kc], krl, m2, 0,0,0);
                m2 = __builtin_amdgcn_mfma_f32_16x16x32_bf16(qf[3][kc], krh, m2, 0,0,0);
                m2 = __builtin_amdgcn_mfma_f32_16x16x32_bf16(qf[0][kc], nkih, m2, 0,0,0);
                m2 = __builtin_amdgcn_mfma_f32_16x16x32_bf16(qf[0][kc], nkil, m2, 0,0,0);
                m2 = __builtin_amdgcn_mfma_f32_16x16x32_bf16(qf[1][kc], nkih, m2, 0,0,0);
                sRe[f] = r; sIm[f] = m2;
            }
        }
        __builtin_amdgcn_s_setprio(0);

        // ---- online softmax + rotor (T13 defer-max); pack P to LDS bf16 ----
        float esc[4];
        int anyUp = 0;
        #pragma unroll
        for (int i = 0; i < 4; ++i) {
            float s0 = sRe[0][i], s1 = sRe[1][i];
            float tmax = fmaxf(s0, s1);
            #pragma unroll
            for (int mm = 1; mm < 16; mm <<= 1) tmax = fmaxf(tmax, __shfl_xor(tmax, mm, 16));
            const int up = tmax > mrow[i] + 8.f;
            float mnew = up ? tmax : mrow[i];
            float p0 = __expf(s0 - mnew);
            float p1 = __expf(s1 - mnew);
            float ps = p0 + p1;
            #pragma unroll
            for (int mm = 1; mm < 16; mm <<= 1) ps += __shfl_xor(ps, mm, 16);
            esc[i]  = up ? __expf(mrow[i] - mnew) : 1.f;
            anyUp  |= up;
            lsum[i] = lsum[i]*esc[i] + ps;
            mrow[i] = mnew;
            float sn0, cs0, sn1, cs1;
            __sincosf(sIm[0][i], &sn0, &cs0);
            __sincosf(sIm[1][i], &sn1, &cs1);
            const int row = g*4 + i;
            Pa[w][row][lq]      = (__bf16)(p0*cs0);
            Pa[w][row][16 + lq] = (__bf16)(p1*cs1);
            Pb[w][row][lq]      = (__bf16)(p0*sn0);
            Pb[w][row][16 + lq] = (__bf16)(p1*sn1);
        }
        if (__any(anyUp)) {
            #pragma unroll
            for (int d = 0; d < 4; ++d)
                #pragma unroll
                for (int i = 0; i < 4; ++i) { oRe[d][i] *= esc[i]; oIm[d][i] *= esc[i]; }
        }

        // ---- PV: O[16q][64d] += P * V  (plain bf16) ----
        bf16x8 pa  = *(const bf16x8*)&Pa[w][lq][g*8];
        bf16x8 pb  = *(const bf16x8*)&Pb[w][lq][g*8];
        bf16x8 npb = neg8(pb);
        __builtin_amdgcn_s_setprio(1);
        #pragma unroll
        for (int df = 0; df < 4; ++df) {
            bf16x8 vr = *(const bf16x8*)&Vs[0][df*16 + lq][g*8];
            bf16x8 vi = *(const bf16x8*)&Vs[1][df*16 + lq][g*8];
            oRe[df] = __builtin_amdgcn_mfma_f32_16x16x32_bf16(pa,  vr, oRe[df], 0,0,0);
            oRe[df] = __builtin_amdgcn_mfma_f32_16x16x32_bf16(npb, vi, oRe[df], 0,0,0);
            oIm[df] = __builtin_amdgcn_mfma_f32_16x16x32_bf16(pa,  vi, oIm[df], 0,0,0);
            oIm[df] = __builtin_amdgcn_mfma_f32_16x16x32_bf16(pb,  vr, oIm[df], 0,0,0);
        }
        __builtin_amdgcn_s_setprio(0);
    }

    // ---- normalize + store directly as 4 split-bf16 planes ----
    #pragma unroll
    for (int i = 0; i < 4; ++i) {
        const float inv = 1.f / lsum[i];
        const size_t rowOff = (size_t)(b*1024 + q0 + w*16 + g*4 + i) * 1024 + h*64;
        #pragma unroll
        for (int df = 0; df < 4; ++df) {
            float re = oRe[df][i] * inv;
            float im = oIm[df][i] * inv;
            __bf16 h1 = (__bf16)re; __bf16 l1 = (__bf16)(re - (float)h1);
            __bf16 h2 = (__bf16)im; __bf16 l2 = (__bf16)(im - (float)h2);
            size_t off = rowOff + df*16 + lq;
            Os[off]         = h1;
            Os[P2M + off]   = l1;
            Os[2*P2M + off] = h2;
            Os[3*P2M + off] = l2;
        }
    }
}

// ---------------------------------------------------------------------------
extern "C" void kernel_launch(void* const* d_in, const int* in_sizes, int n_in,
                              void* d_out, int out_size, void* d_ws, size_t ws_size,
                              hipStream_t stream)
{
    (void)in_sizes; (void)n_in; (void)out_size; (void)ws_size;
    const float* x_re  = (const float*)d_in[0];
    const float* x_im  = (const float*)d_in[1];
    const float* wq_re = (const float*)d_in[2];
    const float* wq_im = (const float*)d_in[3];
    const float* wk_re = (const float*)d_in[4];
    const float* wk_im = (const float*)d_in[5];
    const float* wv_re = (const float*)d_in[6];
    const float* wv_im = (const float*)d_in[7];
    const float* wo_re = (const float*)d_in[8];
    const float* wo_im = (const float*)d_in[9];
    float* out = (float*)d_out;

    char* wsb = (char*)d_ws;
    const size_t MB = (size_t)1 << 20;
    // [0,16)   x_s (bf16 4 planes)     -> after QKV: Vt @0 (8MB)
    // [16,40)  wqkv_s (bf16 4x3M)      -> after QKV: Os (4 planes, 16MB) @16
    // [40,48)  wo_s (bf16 4x1M)
    // [48,64)  Q planes (bf16 4x2M)
    // [64,80)  K planes (bf16 4x2M)
    // [80,88)  V planar bf16 (2x2M)
    __bf16* x_s    = (__bf16*)(wsb +  0*MB);
    __bf16* Vt_g   = (__bf16*)(wsb +  0*MB);
    __bf16* wqkv_s = (__bf16*)(wsb + 16*MB);
    __bf16* Os_g   = (__bf16*)(wsb + 16*MB);
    __bf16* wo_s   = (__bf16*)(wsb + 40*MB);
    __bf16* Qs_g   = (__bf16*)(wsb + 48*MB);
    __bf16* Ks_g   = (__bf16*)(wsb + 64*MB);
    __bf16* Vb_g   = (__bf16*)(wsb + 80*MB);

    const size_t P1M = (size_t)1024 * 1024;
    const size_t P2M = 2 * P1M;
    const size_t P3M = 3 * P1M;

    split_bf16<<<1024, 256, 0, stream>>>(x_re, x_im, x_s, P2M, (int)(P2M/8));
    split_bf16<<< 512, 256, 0, stream>>>(wq_re, wq_im, wqkv_s,         P3M, (int)(P1M/8));
    split_bf16<<< 512, 256, 0, stream>>>(wk_re, wk_im, wqkv_s + P1M,   P3M, (int)(P1M/8));
    split_bf16<<< 512, 256, 0, stream>>>(wv_re, wv_im, wqkv_s + 2*P1M, P3M, (int)(P1M/8));
    split_bf16<<< 512, 256, 0, stream>>>(wo_re, wo_im, wo_s, P1M, (int)(P1M/8));

    // fused QKV projection: Q/K -> RoPE'd split-bf16 planes, V -> bf16 planar
    cgemm_mfma<1><<<dim3(16, 48), 256, 0, stream>>>(x_s, wqkv_s, P3M,
                                                    Qs_g, Ks_g, Vb_g, nullptr);
    // V transpose to per-head [d][s] bf16 (into dead x_s region)
    transpose_v<<<dim3(16, 32), 256, 0, stream>>>(Vb_g, Vt_g);
    // MFMA flash attention -> split-bf16 O planes (into dead wqkv region)
    flash_mfma<<<dim3(32, 32), 128, 0, stream>>>(Qs_g, Ks_g, Vt_g, Os_g);
    // O projection with interleaved (re,im) store
    cgemm_mfma<2><<<dim3(16, 16), 256, 0, stream>>>(Os_g, wo_s, P1M,
                                                    nullptr, nullptr, nullptr, out);
}

// Round 6
// 302.257 us; speedup vs baseline: 4.5592x; 1.0309x over previous
//
#include <hip/hip_runtime.h>
#include <math.h>

#define S_LEN  1024
#define DMODEL 1024
#define DH     64

typedef float  f4     __attribute__((ext_vector_type(4)));
typedef float  f32x4  __attribute__((ext_vector_type(4)));
typedef __bf16 bf16x4 __attribute__((ext_vector_type(4)));
typedef __bf16 bf16x8 __attribute__((ext_vector_type(8)));
typedef unsigned int u32x4 __attribute__((ext_vector_type(4)));

__device__ __forceinline__ bf16x8 neg8(bf16x8 v) {
    u32x4 u;
    __builtin_memcpy(&u, &v, 16);
    u ^= 0x80008000u;
    bf16x8 r;
    __builtin_memcpy(&r, &u, 16);
    return r;
}

// ---------------------------------------------------------------------------
// Split-bf16 complex GEMM via MFMA: C[M=2048, N] = A[2048,1024] * B[N,1024]^T
// A, B are fp32 (re,im) arrays; the hi/lo bf16 split happens during LDS
// staging (2 fp32 arrays == 4 bf16 planes in bytes -> traffic-neutral).
// EPI 1 (QKV): seg = n0>>10 selects B pair (wq/wk/wv) and epilogue:
//   seg 0 (Q): scale 1/8, RoPE, split -> 4 bf16 planes qp
//   seg 1 (K): RoPE, split -> 4 bf16 planes kp
//   seg 2 (V): plain bf16 planar store (2 planes in vb)
// EPI 2: interleaved (re,im) fp32 store to outI (B pair 0 = wo).
// ---------------------------------------------------------------------------
template<int EPI>
__global__ __launch_bounds__(256, 2)
void cgemm_mfma(const float* __restrict__ Are, const float* __restrict__ Aim,
                const float* __restrict__ B0re, const float* __restrict__ B0im,
                const float* __restrict__ B1re, const float* __restrict__ B1im,
                const float* __restrict__ B2re, const float* __restrict__ B2im,
                __bf16* __restrict__ qp, __bf16* __restrict__ kp,
                __bf16* __restrict__ vb, float* __restrict__ outI)
{
    __shared__ __bf16 As[4*128*32];
    __shared__ __bf16 Bs[4*64*32];

    const int tid  = threadIdx.x;
    const int lane = tid & 63;
    const int wid  = tid >> 6;
    const int wm   = wid >> 1, wn = wid & 1;
    const int lrow = lane & 15, lk = lane >> 4;
    const int m0   = blockIdx.x * 128;
    const int n0   = blockIdx.y * 64;
    const int seg  = n0 >> 10;
    const int nloc = n0 & 1023;
    const size_t P2M = (size_t)2048 * 1024;

    const float* bre = B0re; const float* bim = B0im;
    if (EPI == 1) {
        if (seg == 1)      { bre = B1re; bim = B1im; }
        else if (seg == 2) { bre = B2re; bim = B2im; }
    }

    f32x4 accRe[4][2], accIm[4][2];
    #pragma unroll
    for (int i = 0; i < 4; ++i)
        #pragma unroll
        for (int j = 0; j < 2; ++j) {
            accRe[i][j] = (f32x4){0.f,0.f,0.f,0.f};
            accIm[i][j] = (f32x4){0.f,0.f,0.f,0.f};
        }

    // ---- staging: fp32 loads, split to bf16 hi/lo planes at LDS-write ----
    // A: planes {0:hr,1:lr,2:hi,3:li} of [128][32]; B: same of [64][32].
    f4 prA[8], prB[4];
    #pragma unroll
    for (int i = 0; i < 8; ++i) {
        int c = tid + 256*(i & 3);          // 0..1023
        int row = c >> 3, kf = c & 7;
        const float* src = (i < 4) ? Are : Aim;
        prA[i] = *(const f4*)(src + (size_t)(m0+row)*1024 + kf*4);
    }
    #pragma unroll
    for (int i = 0; i < 4; ++i) {
        int c = tid + 256*(i & 1);          // 0..511
        int row = c >> 3, kf = c & 7;
        const float* src = (i < 2) ? bre : bim;
        prB[i] = *(const f4*)(src + (size_t)(nloc+row)*1024 + kf*4);
    }

    const int phys = (lk ^ ((lrow >> 1) & 3)) << 3;

    for (int it = 0; it < 32; ++it) {
        __syncthreads();
        #pragma unroll
        for (int i = 0; i < 8; ++i) {
            int c = tid + 256*(i & 3);
            int row = c >> 3, kf = c & 7;
            int ks = kf >> 1, hf = kf & 1;
            f4 v = prA[i];
            bf16x4 hi, lo;
            #pragma unroll
            for (int j = 0; j < 4; ++j) {
                __bf16 h = (__bf16)v[j];
                hi[j] = h; lo[j] = (__bf16)(v[j] - (float)h);
            }
            int base = (((i < 4 ? 0 : 2)*128 + row)*32) + ((ks ^ ((row>>1)&3)) << 3) + hf*4;
            *(bf16x4*)&As[base]          = hi;
            *(bf16x4*)&As[base + 128*32] = lo;
        }
        #pragma unroll
        for (int i = 0; i < 4; ++i) {
            int c = tid + 256*(i & 1);
            int row = c >> 3, kf = c & 7;
            int ks = kf >> 1, hf = kf & 1;
            f4 v = prB[i];
            bf16x4 hi, lo;
            #pragma unroll
            for (int j = 0; j < 4; ++j) {
                __bf16 h = (__bf16)v[j];
                hi[j] = h; lo[j] = (__bf16)(v[j] - (float)h);
            }
            int base = (((i < 2 ? 0 : 2)*64 + row)*32) + ((ks ^ ((row>>1)&3)) << 3) + hf*4;
            *(bf16x4*)&Bs[base]         = hi;
            *(bf16x4*)&Bs[base + 64*32] = lo;
        }
        __syncthreads();
        if (it < 31) {
            const int k0 = (it + 1) * 32;
            #pragma unroll
            for (int i = 0; i < 8; ++i) {
                int c = tid + 256*(i & 3);
                int row = c >> 3, kf = c & 7;
                const float* src = (i < 4) ? Are : Aim;
                prA[i] = *(const f4*)(src + (size_t)(m0+row)*1024 + k0 + kf*4);
            }
            #pragma unroll
            for (int i = 0; i < 4; ++i) {
                int c = tid + 256*(i & 1);
                int row = c >> 3, kf = c & 7;
                const float* src = (i < 2) ? bre : bim;
                prB[i] = *(const f4*)(src + (size_t)(nloc+row)*1024 + k0 + kf*4);
            }
        }
        bf16x8 bw[2][4];
        #pragma unroll
        for (int nf = 0; nf < 2; ++nf)
            #pragma unroll
            for (int mat = 0; mat < 4; ++mat)
                bw[nf][mat] = *(const bf16x8*)&Bs[(mat*64 + wn*32 + nf*16 + lrow)*32 + phys];
        #pragma unroll
        for (int mf = 0; mf < 4; ++mf) {
            const int arow = wm*64 + mf*16 + lrow;
            bf16x8 xhr = *(const bf16x8*)&As[(0*128 + arow)*32 + phys];
            bf16x8 xlr = *(const bf16x8*)&As[(1*128 + arow)*32 + phys];
            bf16x8 xhi = *(const bf16x8*)&As[(2*128 + arow)*32 + phys];
            bf16x8 xli = *(const bf16x8*)&As[(3*128 + arow)*32 + phys];
            bf16x8 nhi = neg8(xhi), nli = neg8(xli);
            #pragma unroll
            for (int nf = 0; nf < 2; ++nf) {
                f32x4 r  = accRe[mf][nf];
                f32x4 m2 = accIm[mf][nf];
                r  = __builtin_amdgcn_mfma_f32_16x16x32_bf16(xhr, bw[nf][0], r, 0,0,0);
                r  = __builtin_amdgcn_mfma_f32_16x16x32_bf16(xhr, bw[nf][1], r, 0,0,0);
                r  = __builtin_amdgcn_mfma_f32_16x16x32_bf16(xlr, bw[nf][0], r, 0,0,0);
                r  = __builtin_amdgcn_mfma_f32_16x16x32_bf16(nhi, bw[nf][2], r, 0,0,0);
                r  = __builtin_amdgcn_mfma_f32_16x16x32_bf16(nhi, bw[nf][3], r, 0,0,0);
                r  = __builtin_amdgcn_mfma_f32_16x16x32_bf16(nli, bw[nf][2], r, 0,0,0);
                m2 = __builtin_amdgcn_mfma_f32_16x16x32_bf16(xhr, bw[nf][2], m2, 0,0,0);
                m2 = __builtin_amdgcn_mfma_f32_16x16x32_bf16(xhr, bw[nf][3], m2, 0,0,0);
                m2 = __builtin_amdgcn_mfma_f32_16x16x32_bf16(xlr, bw[nf][2], m2, 0,0,0);
                m2 = __builtin_amdgcn_mfma_f32_16x16x32_bf16(xhi, bw[nf][0], m2, 0,0,0);
                m2 = __builtin_amdgcn_mfma_f32_16x16x32_bf16(xhi, bw[nf][1], m2, 0,0,0);
                m2 = __builtin_amdgcn_mfma_f32_16x16x32_bf16(xli, bw[nf][0], m2, 0,0,0);
                accRe[mf][nf] = r; accIm[mf][nf] = m2;
            }
        }
    }

    #pragma unroll
    for (int mf = 0; mf < 4; ++mf) {
        #pragma unroll
        for (int nf = 0; nf < 2; ++nf) {
            const int colB = wn*32 + nf*16 + lrow;   // 0..63 == dh
            f32x4 r  = accRe[mf][nf];
            f32x4 m2 = accIm[mf][nf];
            float invf = 0.f;
            if (EPI == 1 && seg < 2) invf = __expf(-(float)colB * 0.14391157f); // ln(1e4)/64
            #pragma unroll
            for (int rg = 0; rg < 4; ++rg) {
                const int m = m0 + wm*64 + mf*16 + lk*4 + rg;
                float re = r[rg], im = m2[rg];
                if (EPI == 1) {
                    if (seg == 0) { re *= 0.125f; im *= 0.125f; }  // fold 1/sqrt(Dh) into Q
                    if (seg < 2) {
                        float sn, cs;
                        __sincosf((float)(m & (S_LEN-1)) * invf, &sn, &cs);
                        float t = re*cs - im*sn;
                        im = re*sn + im*cs; re = t;
                        __bf16 h1 = (__bf16)re; __bf16 l1 = (__bf16)(re - (float)h1);
                        __bf16 h2 = (__bf16)im; __bf16 l2 = (__bf16)(im - (float)h2);
                        __bf16* dp = (seg == 0) ? qp : kp;
                        size_t off = (size_t)m*1024 + nloc + colB;
                        dp[off] = h1; dp[P2M + off] = l1;
                        dp[2*P2M + off] = h2; dp[3*P2M + off] = l2;
                    } else {
                        size_t off = (size_t)m*1024 + nloc + colB;
                        vb[off] = (__bf16)re; vb[P2M + off] = (__bf16)im;
                    }
                } else {
                    size_t off = ((size_t)m*1024 + nloc + colB)*2;
                    outI[off] = re; outI[off+1] = im;
                }
            }
        }
    }
}

// ---------------------------------------------------------------------------
// V transpose prep: bf16 planar V[2][2048][1024] -> bf16 Vt[2][32bh][64 d][1024 s]
// ---------------------------------------------------------------------------
__global__ __launch_bounds__(256)
void transpose_v(const __bf16* __restrict__ Vb, __bf16* __restrict__ Vt)
{
    __shared__ __bf16 T[2][64][72];
    const int tid = threadIdx.x;
    const int s0  = blockIdx.x * 64;
    const int bh  = blockIdx.y;
    const int b   = bh >> 4, h = bh & 15;
    const size_t P2M = (size_t)2048 * 1024;

    #pragma unroll
    for (int i = 0; i < 4; ++i) {
        int c = tid + 256*i;            // 0..1023
        int p = c >> 9, row = (c >> 3) & 63, cc = c & 7;
        bf16x8 v = *(const bf16x8*)(Vb + (size_t)p*P2M + (size_t)(b*1024 + s0 + row)*1024 + h*64 + cc*8);
        *(bf16x8*)&T[p][row][cc*8] = v;
    }
    __syncthreads();
    #pragma unroll
    for (int i = 0; i < 4; ++i) {
        int c = tid + 256*i;
        int p = c >> 9, d = (c >> 3) & 63, sc = c & 7;
        bf16x8 o;
        #pragma unroll
        for (int j = 0; j < 8; ++j) o[j] = T[p][sc*8+j][d];
        *(bf16x8*)(Vt + (size_t)p*P2M + (size_t)(bh*64 + d)*1024 + s0 + sc*8) = o;
    }
}

// ---------------------------------------------------------------------------
// MFMA flash attention.
// grid (S/32, 32 bh), 128 threads = 2 waves; wave w owns queries q0+w*16..+15.
// KVBLK=32, 1024 blocks (4/CU). QK^H split-bf16, PV plain bf16.
// T13 defer-max (THR=8), T5 setprio around MFMA clusters.
// Epilogue: fp32 planar O (split into bf16 happens in O-proj staging).
// ---------------------------------------------------------------------------
__global__ __launch_bounds__(128, 2)
void flash_mfma(const __bf16* __restrict__ Qp, const __bf16* __restrict__ Kp,
                const __bf16* __restrict__ Vt,
                float* __restrict__ Ore, float* __restrict__ Oim)
{
    __shared__ __align__(16) __bf16 Ks[4][32][72];   // [plane][key][dh] pad
    __shared__ __align__(16) __bf16 Vs[2][64][40];   // [plane][d][key] pad
    __shared__ __align__(16) __bf16 Pa[2][16][40];   // per-wave P real
    __shared__ __align__(16) __bf16 Pb[2][16][40];   // per-wave P imag

    const int tid  = threadIdx.x;
    const int lane = tid & 63;
    const int w    = tid >> 6;
    const int lq   = lane & 15;
    const int g    = lane >> 4;       // 0..3
    const int q0   = blockIdx.x * 32;
    const int bh   = blockIdx.y;
    const int b    = bh >> 4, h = bh & 15;
    const size_t P2M = (size_t)2048 * 1024;

    // ---- persistent Q fragments: qf[plane][kchunk] ----
    bf16x8 qf[4][2];
    {
        const size_t qrow = (size_t)(b*1024 + q0 + w*16 + lq) * 1024 + h*64;
        #pragma unroll
        for (int p = 0; p < 4; ++p)
            #pragma unroll
            for (int kc = 0; kc < 2; ++kc)
                qf[p][kc] = *(const bf16x8*)(Qp + (size_t)p*P2M + qrow + kc*32 + g*8);
    }

    f32x4 oRe[4], oIm[4];
    #pragma unroll
    for (int d = 0; d < 4; ++d) { oRe[d] = (f32x4){0,0,0,0}; oIm[d] = (f32x4){0,0,0,0}; }
    float mrow[4], lsum[4];
    #pragma unroll
    for (int i = 0; i < 4; ++i) { mrow[i] = -INFINITY; lsum[i] = 0.f; }

    // ---- prefetch K/V tile 0 ----
    bf16x8 pk[8]; bf16x8 pv[4];
    #pragma unroll
    for (int i = 0; i < 8; ++i) {
        int c = tid + 128*i;            // 0..1023
        int p = c >> 8, key = (c >> 3) & 31, cc = c & 7;
        pk[i] = *(const bf16x8*)(Kp + (size_t)p*P2M + (size_t)(b*1024 + key)*1024 + h*64 + cc*8);
    }
    #pragma unroll
    for (int i = 0; i < 4; ++i) {
        int c = tid + 128*i;            // 0..511
        int p = c >> 8, d = (c >> 2) & 63, cc = c & 3;
        pv[i] = *(const bf16x8*)(Vt + (size_t)p*P2M + (size_t)(bh*64 + d)*1024 + cc*8);
    }

    for (int it = 0; it < 32; ++it) {
        __syncthreads();
        // ---- write staged K/V from regs ----
        #pragma unroll
        for (int i = 0; i < 8; ++i) {
            int c = tid + 128*i;
            int p = c >> 8, key = (c >> 3) & 31, cc = c & 7;
            *(bf16x8*)&Ks[p][key][cc*8] = pk[i];
        }
        #pragma unroll
        for (int i = 0; i < 4; ++i) {
            int c = tid + 128*i;
            int p = c >> 8, d = (c >> 2) & 63, cc = c & 3;
            *(bf16x8*)&Vs[p][d][cc*8] = pv[i];
        }
        // ---- issue next-tile prefetch ----
        if (it < 31) {
            const int t0 = (it + 1) * 32;
            #pragma unroll
            for (int i = 0; i < 8; ++i) {
                int c = tid + 128*i;
                int p = c >> 8, key = (c >> 3) & 31, cc = c & 7;
                pk[i] = *(const bf16x8*)(Kp + (size_t)p*P2M + (size_t)(b*1024 + t0 + key)*1024 + h*64 + cc*8);
            }
            #pragma unroll
            for (int i = 0; i < 4; ++i) {
                int c = tid + 128*i;
                int p = c >> 8, d = (c >> 2) & 63, cc = c & 3;
                pv[i] = *(const bf16x8*)(Vt + (size_t)p*P2M + (size_t)(bh*64 + d)*1024 + t0 + cc*8);
            }
        }
        __syncthreads();

        // ---- QK^H: S[16q][32k] split-bf16, fp32 accum ----
        f32x4 sRe[2], sIm[2];
        #pragma unroll
        for (int f = 0; f < 2; ++f) { sRe[f] = (f32x4){0,0,0,0}; sIm[f] = (f32x4){0,0,0,0}; }
        __builtin_amdgcn_s_setprio(1);
        #pragma unroll
        for (int kc = 0; kc < 2; ++kc) {
            #pragma unroll
            for (int f = 0; f < 2; ++f) {
                const int key = f*16 + lq;
                bf16x8 krh = *(const bf16x8*)&Ks[0][key][kc*32 + g*8];
                bf16x8 krl = *(const bf16x8*)&Ks[1][key][kc*32 + g*8];
                bf16x8 kih = *(const bf16x8*)&Ks[2][key][kc*32 + g*8];
                bf16x8 kil = *(const bf16x8*)&Ks[3][key][kc*32 + g*8];
                bf16x8 nkih = neg8(kih), nkil = neg8(kil);
                f32x4 r = sRe[f], m2 = sIm[f];
                r  = __builtin_amdgcn_mfma_f32_16x16x32_bf16(qf[0][kc], krh, r, 0,0,0);
                r  = __builtin_amdgcn_mfma_f32_16x16x32_bf16(qf[0][kc], krl, r, 0,0,0);
                r  = __builtin_amdgcn_mfma_f32_16x16x32_bf16(qf[1][kc], krh, r, 0,0,0);
                r  = __builtin_amdgcn_mfma_f32_16x16x32_bf16(qf[2][kc], kih, r, 0,0,0);
                r  = __builtin_amdgcn_mfma_f32_16x16x32_bf16(qf[2][kc], kil, r, 0,0,0);
                r  = __builtin_amdgcn_mfma_f32_16x16x32_bf16(qf[3][kc], kih, r, 0,0,0);
                m2 = __builtin_amdgcn_mfma_f32_16x16x32_bf16(qf[2][kc], krh, m2, 0,0,0);
                m2 = __builtin_amdgcn_mfma_f32_16x16x32_bf16(qf[2][kc], krl, m2, 0,0,0);
                m2 = __builtin_amdgcn_mfma_f32_16x16x32_bf16(qf[3][kc], krh, m2, 0,0,0);
                m2 = __builtin_amdgcn_mfma_f32_16x16x32_bf16(qf[0][kc], nkih, m2, 0,0,0);
                m2 = __builtin_amdgcn_mfma_f32_16x16x32_bf16(qf[0][kc], nkil, m2, 0,0,0);
                m2 = __builtin_amdgcn_mfma_f32_16x16x32_bf16(qf[1][kc], nkih, m2, 0,0,0);
                sRe[f] = r; sIm[f] = m2;
            }
        }
        __builtin_amdgcn_s_setprio(0);

        // ---- online softmax + rotor (T13 defer-max); pack P to LDS bf16 ----
        float esc[4];
        int anyUp = 0;
        #pragma unroll
        for (int i = 0; i < 4; ++i) {
            float s0 = sRe[0][i], s1 = sRe[1][i];
            float tmax = fmaxf(s0, s1);
            #pragma unroll
            for (int mm = 1; mm < 16; mm <<= 1) tmax = fmaxf(tmax, __shfl_xor(tmax, mm, 16));
            const int up = tmax > mrow[i] + 8.f;
            float mnew = up ? tmax : mrow[i];
            float p0 = __expf(s0 - mnew);
            float p1 = __expf(s1 - mnew);
            float ps = p0 + p1;
            #pragma unroll
            for (int mm = 1; mm < 16; mm <<= 1) ps += __shfl_xor(ps, mm, 16);
            esc[i]  = up ? __expf(mrow[i] - mnew) : 1.f;
            anyUp  |= up;
            lsum[i] = lsum[i]*esc[i] + ps;
            mrow[i] = mnew;
            float sn0, cs0, sn1, cs1;
            __sincosf(sIm[0][i], &sn0, &cs0);
            __sincosf(sIm[1][i], &sn1, &cs1);
            const int row = g*4 + i;
            Pa[w][row][lq]      = (__bf16)(p0*cs0);
            Pa[w][row][16 + lq] = (__bf16)(p1*cs1);
            Pb[w][row][lq]      = (__bf16)(p0*sn0);
            Pb[w][row][16 + lq] = (__bf16)(p1*sn1);
        }
        if (__any(anyUp)) {
            #pragma unroll
            for (int d = 0; d < 4; ++d)
                #pragma unroll
                for (int i = 0; i < 4; ++i) { oRe[d][i] *= esc[i]; oIm[d][i] *= esc[i]; }
        }

        // ---- PV: O[16q][64d] += P * V  (plain bf16) ----
        bf16x8 pa  = *(const bf16x8*)&Pa[w][lq][g*8];
        bf16x8 pb  = *(const bf16x8*)&Pb[w][lq][g*8];
        bf16x8 npb = neg8(pb);
        __builtin_amdgcn_s_setprio(1);
        #pragma unroll
        for (int df = 0; df < 4; ++df) {
            bf16x8 vr = *(const bf16x8*)&Vs[0][df*16 + lq][g*8];
            bf16x8 vi = *(const bf16x8*)&Vs[1][df*16 + lq][g*8];
            oRe[df] = __builtin_amdgcn_mfma_f32_16x16x32_bf16(pa,  vr, oRe[df], 0,0,0);
            oRe[df] = __builtin_amdgcn_mfma_f32_16x16x32_bf16(npb, vi, oRe[df], 0,0,0);
            oIm[df] = __builtin_amdgcn_mfma_f32_16x16x32_bf16(pa,  vi, oIm[df], 0,0,0);
            oIm[df] = __builtin_amdgcn_mfma_f32_16x16x32_bf16(pb,  vr, oIm[df], 0,0,0);
        }
        __builtin_amdgcn_s_setprio(0);
    }

    // ---- normalize + store fp32 planar ----
    #pragma unroll
    for (int i = 0; i < 4; ++i) {
        const float inv = 1.f / lsum[i];
        const size_t rowOff = (size_t)(b*1024 + q0 + w*16 + g*4 + i) * 1024 + h*64;
        #pragma unroll
        for (int df = 0; df < 4; ++df) {
            Ore[rowOff + df*16 + lq] = oRe[df][i] * inv;
            Oim[rowOff + df*16 + lq] = oIm[df][i] * inv;
        }
    }
}

// ---------------------------------------------------------------------------
extern "C" void kernel_launch(void* const* d_in, const int* in_sizes, int n_in,
                              void* d_out, int out_size, void* d_ws, size_t ws_size,
                              hipStream_t stream)
{
    (void)in_sizes; (void)n_in; (void)out_size; (void)ws_size;
    const float* x_re  = (const float*)d_in[0];
    const float* x_im  = (const float*)d_in[1];
    const float* wq_re = (const float*)d_in[2];
    const float* wq_im = (const float*)d_in[3];
    const float* wk_re = (const float*)d_in[4];
    const float* wk_im = (const float*)d_in[5];
    const float* wv_re = (const float*)d_in[6];
    const float* wv_im = (const float*)d_in[7];
    const float* wo_re = (const float*)d_in[8];
    const float* wo_im = (const float*)d_in[9];
    float* out = (float*)d_out;

    char* wsb = (char*)d_ws;
    const size_t MB = (size_t)1 << 20;
    // [0,16)   Q split planes (bf16 4x2M)
    // [16,32)  K split planes (bf16 4x2M)
    // [32,40)  V planar bf16 (2x2M)
    // [40,48)  Vt per-head [d][s] bf16 (2x2M)
    // [48,56)  O re fp32 ; [56,64) O im fp32
    __bf16* Qs_g = (__bf16*)(wsb +  0*MB);
    __bf16* Ks_g = (__bf16*)(wsb + 16*MB);
    __bf16* Vb_g = (__bf16*)(wsb + 32*MB);
    __bf16* Vt_g = (__bf16*)(wsb + 40*MB);
    float*  Ore  = (float*) (wsb + 48*MB);
    float*  Oim  = (float*) (wsb + 56*MB);

    // fused QKV projection (fp32 in, split in staging): Q/K -> RoPE'd
    // split-bf16 planes, V -> bf16 planar
    cgemm_mfma<1><<<dim3(16, 48), 256, 0, stream>>>(
        x_re, x_im, wq_re, wq_im, wk_re, wk_im, wv_re, wv_im,
        Qs_g, Ks_g, Vb_g, nullptr);
    // V transpose to per-head [d][s] bf16
    transpose_v<<<dim3(16, 32), 256, 0, stream>>>(Vb_g, Vt_g);
    // MFMA flash attention -> fp32 planar O
    flash_mfma<<<dim3(32, 32), 128, 0, stream>>>(Qs_g, Ks_g, Vt_g, Ore, Oim);
    // O projection (splits O/wo in staging), interleaved (re,im) store
    cgemm_mfma<2><<<dim3(16, 16), 256, 0, stream>>>(
        Ore, Oim, wo_re, wo_im, nullptr, nullptr, nullptr, nullptr,
        nullptr, nullptr, nullptr, out);
}